// Round 20
// baseline (291.993 us; speedup 1.0000x reference)
//
#include <hip/hip_runtime.h>
#include <hip/hip_bf16.h>
#include <math.h>

#define EPSF 1e-5f

typedef __bf16 v8bf __attribute__((ext_vector_type(8)));
typedef float  v4f  __attribute__((ext_vector_type(4)));
typedef unsigned int u32;
typedef unsigned short u16;

__device__ __forceinline__ float gelu_exact(float x) {
    return 0.5f * x * (1.0f + erff(x * 0.70710678f));
}
__device__ __forceinline__ u16 f2bf(float f) {   // RNE
    u32 u = __float_as_uint(f);
    return (u16)((u + 0x7fffu + ((u >> 16) & 1u)) >> 16);
}
__device__ __forceinline__ float bf2f(u16 u) {
    return __uint_as_float(((u32)u) << 16);
}
__device__ __forceinline__ void gload16(const void* g, void* l) {
    __builtin_amdgcn_global_load_lds((const __attribute__((address_space(1))) u32*)g,
                                     (__attribute__((address_space(3))) u32*)l, 16, 0, 0);
}

// counted-vmcnt barrier: allow N vector-mem ops outstanding, drain LDS ops.
#define BARRIER(N) do { \
    asm volatile("s_waitcnt vmcnt(" #N ") lgkmcnt(0)" ::: "memory"); \
    __builtin_amdgcn_s_barrier(); \
} while (0)

// ---------------------------------------------------------------------------
// Prep: fz_w[o][1536] f32 -> Bz[ec2][h][n][8] bf16 (coalesced reads)
// ---------------------------------------------------------------------------
__global__ __launch_bounds__(256) void kprep_z(const float* __restrict__ fz_w,
                                               u16* __restrict__ Bz) {
    int idx = blockIdx.x * 256 + threadIdx.x;   // 0 .. 73727
    int n = idx / 192;
    int r = idx % 192;
    int ec2 = r >> 2;
    int h = r & 3;
    const float* src = fz_w + (size_t)n * 1536 + ec2 * 32 + h * 8;
    float4 v0 = *(const float4*)src;
    float4 v1 = *(const float4*)(src + 4);
    uint4 pk;
    pk.x = (u32)f2bf(v0.x) | ((u32)f2bf(v0.y) << 16);
    pk.y = (u32)f2bf(v0.z) | ((u32)f2bf(v0.w) << 16);
    pk.z = (u32)f2bf(v1.x) | ((u32)f2bf(v1.y) << 16);
    pk.w = (u32)f2bf(v1.z) | ((u32)f2bf(v1.w) << 16);
    size_t slot = ((size_t)(ec2 * 4 + h) * 384 + n);
    *(uint4*)(Bz + slot * 8) = pk;
}

// ---------------------------------------------------------------------------
// Prep: w[n][e][3][3] f32 -> Bw[conv][s][ec2][h][n][8] bf16.
// ---------------------------------------------------------------------------
__global__ __launch_bounds__(256) void kprep_w(const float* __restrict__ wr,
                                               const float* __restrict__ wi,
                                               u16* __restrict__ Bw) {
    __shared__ float wsm[6912];
    const int tid = threadIdx.x;
    const int n = blockIdx.x >> 1;
    const int conv = blockIdx.x & 1;
    const float* w = (conv ? wi : wr) + (size_t)n * 6912;
#pragma unroll
    for (int k = 0; k < 7; ++k) {
        int sl = tid + k * 256;
        if (sl < 1728) ((float4*)wsm)[sl] = ((const float4*)w)[sl];
    }
    __syncthreads();
#pragma unroll
    for (int k = 0; k < 4; ++k) {
        int sl = tid + k * 256;          // (s*24+ec2)*4 + h
        if (sl < 864) {
            int h = sl & 3;
            int r = sl >> 2;
            int ec2 = r % 24;
            int s = r / 24;
            int ch0 = ec2 * 32 + h * 8;
            u16 tmp[8];
#pragma unroll
            for (int e = 0; e < 8; ++e) tmp[e] = f2bf(wsm[(ch0 + e) * 9 + s]);
            uint4 pk;
            pk.x = (u32)tmp[0] | ((u32)tmp[1] << 16);
            pk.y = (u32)tmp[2] | ((u32)tmp[3] << 16);
            pk.z = (u32)tmp[4] | ((u32)tmp[5] << 16);
            pk.w = (u32)tmp[6] | ((u32)tmp[7] << 16);
            size_t slot = ((size_t)conv * 864 + sl) * 384 + n;
            *(uint4*)(Bw + slot * 8) = pk;
        }
    }
}

// ---------------------------------------------------------------------------
// kz2: z = gelu(LN(concat(z_r,z_i) @ fz_w^T + fz_b)) via MFMA.
// grid (2 t-halves, 128 b), 384 thr = 6 waves. Writes zpk[b][o][t(64)] bf16.
// ---------------------------------------------------------------------------
#define ZB_BUF 24576
#define ZA_BUF 2048

__global__ __launch_bounds__(384, 1) void kz2(const float* __restrict__ z_r,
                                              const float* __restrict__ z_i,
                                              const u16* __restrict__ Bz,
                                              const float* __restrict__ fz_b,
                                              const float* __restrict__ ln_g,
                                              const float* __restrict__ ln_b,
                                              u16* __restrict__ zpk) {
    const int th = blockIdx.x;
    const int b  = blockIdx.y;
    const int tid  = threadIdx.x;
    const int lane = tid & 63;
    const int wid  = tid >> 6;
    const int l15  = lane & 15;
    const int h    = lane >> 4;

    __shared__ __align__(16) char lds[3 * ZB_BUF + 2 * ZA_BUF];   // 77824
    char* ldsZB = lds;
    char* ldsZA = lds + 3 * ZB_BUF;
    __shared__ float redS[6 * 32], redQ[6 * 32], mu_s[32], rs_s[32];

    const float* zr_b = z_r + (size_t)b * (64 * 768);
    const float* zi_b = z_i + (size_t)b * (64 * 768);

    int boff[4];
#pragma unroll
    for (int nj = 0; nj < 4; ++nj) {
        int n = wid * 64 + nj * 16 + l15;
        boff[nj] = h * 6144 + n * 16;
    }
    int zaoff[2];
#pragma unroll
    for (int mi = 0; mi < 2; ++mi)
        zaoff[mi] = h * 512 + (mi * 16 + l15) * 16;

    auto stageZB = [&](int ec2, char* buf) {       // 4 gload16 / thread
        const char* src = (const char*)(Bz + (size_t)ec2 * 1536 * 8);
#pragma unroll
        for (int k = 0; k < 4; ++k) {
            int sl = tid + k * 384;
            gload16(src + sl * 16, buf + sl * 16);
        }
    };
    auto issueZA = [&](int ec2, float4* zr) {      // 1 load / thread (uniform)
        const float* zsrc = (ec2 < 24) ? zr_b : zi_b;
        const int ch0 = (ec2 < 24 ? ec2 : ec2 - 24) * 32;
        int sl = tid & 255;
        int row = sl >> 3, qq = sl & 7;
        zr[0] = *(const float4*)(zsrc + (size_t)(th * 32 + row) * 768 + ch0 + qq * 4);
    };
    auto convertZA = [&](const float4* zr, char* buf) {
        int sl = tid & 255;
        int row = sl >> 3, qq = sl & 7;
        ushort4 pk;
        pk.x = f2bf(zr[0].x); pk.y = f2bf(zr[0].y);
        pk.z = f2bf(zr[0].z); pk.w = f2bf(zr[0].w);
        *(ushort4*)(buf + (qq >> 1) * 512 + row * 16 + (qq & 1) * 8) = pk;
    };

    v4f acc[2][4] = {};

    auto comp = [&](char* curA, char* curB) {
        v8bf a[2], bfv[4];
#pragma unroll
        for (int mi = 0; mi < 2; ++mi) a[mi] = *(const v8bf*)(curA + zaoff[mi]);
#pragma unroll
        for (int nj = 0; nj < 4; ++nj) bfv[nj] = *(const v8bf*)(curB + boff[nj]);
        __builtin_amdgcn_s_setprio(1);
#pragma unroll
        for (int mi = 0; mi < 2; ++mi)
#pragma unroll
            for (int nj = 0; nj < 4; ++nj)
                acc[mi][nj] = __builtin_amdgcn_mfma_f32_16x16x32_bf16(a[mi], bfv[nj], acc[mi][nj], 0, 0, 0);
        __builtin_amdgcn_s_setprio(0);
    };

    float4 zreg[1];
    {
        issueZA(0, zreg);
        stageZB(0, ldsZB);
        stageZB(1, ldsZB + ZB_BUF);
        convertZA(zreg, ldsZA);      // waits ZA(0)
        issueZA(1, zreg);
        BARRIER(5);                  // allow ZB(1)=4 + ZA(1)=1
    }
#pragma unroll 1
    for (int t = 0; t < 46; ++t) {
        stageZB(t + 2, ldsZB + ((t + 2) % 3) * ZB_BUF);
        comp(ldsZA + (t & 1) * ZA_BUF, ldsZB + (t % 3) * ZB_BUF);
        convertZA(zreg, ldsZA + ((t + 1) & 1) * ZA_BUF);  // waits ZA(t+1): vmcnt(4)
        issueZA(t + 2, zreg);
        BARRIER(5);                  // allow ZB(t+2)=4 + ZA(t+2)=1; drains ZB(t+1)
    }
    {   // t = 46
        comp(ldsZA + (46 & 1) * ZA_BUF, ldsZB + (46 % 3) * ZB_BUF);
        convertZA(zreg, ldsZA + (47 & 1) * ZA_BUF);       // waits ZA(47): vmcnt(0)
        BARRIER(0);
    }
    comp(ldsZA + (47 & 1) * ZA_BUF, ldsZB + (47 % 3) * ZB_BUF);

    // ---- bias + LN stats (rows 0..31 local) ----
    float fzb[4], lng[4], lnb[4];
#pragma unroll
    for (int nj = 0; nj < 4; ++nj) {
        int o = wid * 64 + nj * 16 + l15;
        fzb[nj] = fz_b[o]; lng[nj] = ln_g[o]; lnb[nj] = ln_b[o];
    }
#pragma unroll
    for (int mi = 0; mi < 2; ++mi)
#pragma unroll
        for (int nj = 0; nj < 4; ++nj)
#pragma unroll
            for (int reg = 0; reg < 4; ++reg)
                acc[mi][nj][reg] += fzb[nj];

#pragma unroll
    for (int mi = 0; mi < 2; ++mi) {
#pragma unroll
        for (int reg = 0; reg < 4; ++reg) {
            float s = 0.f, q = 0.f;
#pragma unroll
            for (int nj = 0; nj < 4; ++nj) {
                float v = acc[mi][nj][reg];
                s += v; q += v * v;
            }
#pragma unroll
            for (int m = 0; m < 4; ++m) {
                s += __shfl_xor(s, 1 << m, 64);
                q += __shfl_xor(q, 1 << m, 64);
            }
            if (l15 == 0) {
                int row = mi * 16 + h * 4 + reg;
                redS[wid * 32 + row] = s;
                redQ[wid * 32 + row] = q;
            }
        }
    }
    __syncthreads();
    if (tid < 32) {
        float s = 0.f, q = 0.f;
#pragma unroll
        for (int w6 = 0; w6 < 6; ++w6) { s += redS[w6 * 32 + tid]; q += redQ[w6 * 32 + tid]; }
        float mu = s * (1.0f / 384.0f);
        float var = q * (1.0f / 384.0f) - mu * mu;
        mu_s[tid] = mu;
        rs_s[tid] = rsqrtf(var + EPSF);
    }
    __syncthreads();

    // ---- LN + gelu -> zpk[b][o][t] ----
#pragma unroll
    for (int mi = 0; mi < 2; ++mi)
#pragma unroll
        for (int nj = 0; nj < 4; ++nj) {
            int o = wid * 64 + nj * 16 + l15;
            u32* dst = (u32*)zpk + ((size_t)b * 384 + o) * 32 + th * 16 + mi * 8 + h * 2;
#pragma unroll
            for (int rp = 0; rp < 2; ++rp) {
                float zv[2];
#pragma unroll
                for (int k = 0; k < 2; ++k) {
                    int reg = rp * 2 + k;
                    int row = mi * 16 + h * 4 + reg;
                    float v = (acc[mi][nj][reg] - mu_s[row]) * rs_s[row] * lng[nj] + lnb[nj];
                    zv[k] = gelu_exact(v);
                }
                dst[rp] = (u32)f2bf(zv[0]) | ((u32)f2bf(zv[1]) << 16);
            }
        }
}

// ---------------------------------------------------------------------------
// kc17: kc14 body, K-split across blocks. block = (kh, conv, b); 12 ec2 each.
// 768 thr = 12 waves, wave tile 64x32. grid 512 = 2 blocks/CU = 24 waves/CU.
// Writes bf16 conv partials P[(kh*2+conv)][b][pix][o]; epilogue in ke.
// ---------------------------------------------------------------------------
#define APL14  2816            // A h-plane stride (176*16)
#define ABUF14 (4 * APL14)     // 11264 per ec2 buffer
#define SSTR14 589824          // 24 * 24576 : tap-s stride in Bw
#define ESTR14 24576           // ec2 stride in Bw

__global__ __launch_bounds__(768, 6) void kc17(const float* __restrict__ x_r,
                                               const float* __restrict__ x_i,
                                               const u16* __restrict__ Bw,
                                               u16* __restrict__ P) {
    const int q    = blockIdx.x;        // kh*2 + conv
    const int kh   = q >> 1;
    const int conv = q & 1;
    const int b    = blockIdx.y;
    const int tid  = threadIdx.x;
    const int lane = tid & 63;
    const int wid  = tid >> 6;          // 0..11 = 32-col group
    const int l15  = lane & 15;
    const int h    = lane >> 4;         // 0..3
    const int e0   = kh * 12;

    __shared__ __align__(16) char ldsA[2 * ABUF14];   // 22528

    const float* x  = conv ? x_i : x_r;
    const float* xb = x + (size_t)b * (256 * 768);

    const char* bbase = (const char*)(Bw + (size_t)conv * (864 * 384 * 8))
                      + (size_t)h * 6144 + (wid * 32 + l15) * 16;

    int aoff[4];
#pragma unroll
    for (int mi = 0; mi < 4; ++mi) {
        int p = mi * 16 + l15;
        int i = p >> 3, j = p & 7;
        aoff[mi] = h * APL14 + (i * 16 + j + 3) * 16;
    }

    auto issueA = [&](int ec2, float4* ar) {          // 2 loads/thread (wrapped dup)
#pragma unroll
        for (int k = 0; k < 2; ++k) {
            int sl = tid + k * 768;
            if (sl >= 1408) sl -= 1408;
            int row = sl >> 3, qq = sl & 7;
            ar[k] = *(const float4*)(xb + (size_t)(48 + row) * 768 + ec2 * 32 + qq * 4);
        }
    };
    auto convertA = [&](const float4* ar, char* buf) {
#pragma unroll
        for (int k = 0; k < 2; ++k) {
            int sl = tid + k * 768;
            if (sl >= 1408) sl -= 1408;
            int row = sl >> 3, qq = sl & 7;
            ushort4 pk;
            pk.x = f2bf(ar[k].x); pk.y = f2bf(ar[k].y);
            pk.z = f2bf(ar[k].z); pk.w = f2bf(ar[k].w);
            *(ushort4*)(buf + (qq >> 1) * APL14 + row * 16 + (qq & 1) * 8) = pk;
        }
    };

    v4f acc[4][2] = {};
    v8bf bpipe[3][2];
    float4 areg[2];

    {   // prologue: A(e0) issued first (oldest), then 6 B loads (taps 0..2)
        issueA(e0, areg);
#pragma unroll
        for (int i = 0; i < 3; ++i) {
            const char* p = bbase + (size_t)e0 * ESTR14 + (size_t)i * SSTR14;
            bpipe[i][0] = *(const v8bf*)p;
            bpipe[i][1] = *(const v8bf*)(p + 256);
        }
        convertA(areg, ldsA);        // reg-dep drains areg (vmcnt<=6); bpipe stays
        BARRIER(6);                  // all 6 B prefetches remain in flight
    }

    // TAP(S): compute tap (e,S); prefetch tap (9e+S+3)'s 2 B frags.
#define TAP(S) do { \
        v8bf b0 = bpipe[(S) % 3][0]; \
        v8bf b1 = bpipe[(S) % 3][1]; \
        const int _so = (((S) / 3) * 16 + ((S) % 3)) * 16; \
        v8bf a0 = *(const v8bf*)(Acur + aoff[0] + _so); \
        v8bf a1 = *(const v8bf*)(Acur + aoff[1] + _so); \
        v8bf a2 = *(const v8bf*)(Acur + aoff[2] + _so); \
        v8bf a3 = *(const v8bf*)(Acur + aoff[3] + _so); \
        __builtin_amdgcn_s_setprio(1); \
        acc[0][0] = __builtin_amdgcn_mfma_f32_16x16x32_bf16(a0, b0, acc[0][0], 0, 0, 0); \
        acc[0][1] = __builtin_amdgcn_mfma_f32_16x16x32_bf16(a0, b1, acc[0][1], 0, 0, 0); \
        acc[1][0] = __builtin_amdgcn_mfma_f32_16x16x32_bf16(a1, b0, acc[1][0], 0, 0, 0); \
        acc[1][1] = __builtin_amdgcn_mfma_f32_16x16x32_bf16(a1, b1, acc[1][1], 0, 0, 0); \
        acc[2][0] = __builtin_amdgcn_mfma_f32_16x16x32_bf16(a2, b0, acc[2][0], 0, 0, 0); \
        acc[2][1] = __builtin_amdgcn_mfma_f32_16x16x32_bf16(a2, b1, acc[2][1], 0, 0, 0); \
        acc[3][0] = __builtin_amdgcn_mfma_f32_16x16x32_bf16(a3, b0, acc[3][0], 0, 0, 0); \
        acc[3][1] = __builtin_amdgcn_mfma_f32_16x16x32_bf16(a3, b1, acc[3][1], 0, 0, 0); \
        __builtin_amdgcn_s_setprio(0); \
        if ((S) <= 5) { \
            const char* _p = bptr + (size_t)((S) + 3) * SSTR14; \
            bpipe[(S) % 3][0] = *(const v8bf*)_p; \
            bpipe[(S) % 3][1] = *(const v8bf*)(_p + 256); \
        } else if (e < e0 + 11) { \
            const char* _p = bptr + ESTR14 + (size_t)((S) - 6) * SSTR14; \
            bpipe[(S) % 3][0] = *(const v8bf*)_p; \
            bpipe[(S) % 3][1] = *(const v8bf*)(_p + 256); \
        } \
    } while (0)

#pragma unroll 1
    for (int e = e0; e < e0 + 12; ++e) {
        const char* Acur = ldsA + (e & 1) * ABUF14;
        const char* bptr = bbase + (size_t)e * ESTR14;
        TAP(0); TAP(1); TAP(2);
        if (e < e0 + 11) issueA(e + 1, areg);
        TAP(3); TAP(4); TAP(5); TAP(6);
        if (e < e0 + 11) convertA(areg, ldsA + ((e + 1) & 1) * ABUF14);  // drains areg
        TAP(7); TAP(8);
        if (e < e0 + 11) BARRIER(6);     // 6 next-ec2 B prefetches stay in flight
    }
#undef TAP

    // ---- store bf16 partials ----
    u16* Pd = P + ((size_t)(q * 128 + b)) * 24576;
#pragma unroll
    for (int nj = 0; nj < 2; ++nj) {
        const int o = wid * 32 + nj * 16 + l15;
#pragma unroll
        for (int mi = 0; mi < 4; ++mi) {
#pragma unroll
            for (int reg = 0; reg < 4; ++reg) {
                int pix = mi * 16 + h * 4 + reg;
                Pd[pix * 384 + o] = f2bf(acc[mi][nj][reg]);
            }
        }
    }
}

// ---------------------------------------------------------------------------
// ke: merge K-halves, BN + gelu + dot(zpk) + sigmoid -> out.
// grid (128 b, 2 conv), 384 thr (thread = o).
// ---------------------------------------------------------------------------
__global__ __launch_bounds__(384) void ke(const u16* __restrict__ P,
                                          const u16* __restrict__ zpk,
                                          const float* __restrict__ br,  const float* __restrict__ bnr_g,
                                          const float* __restrict__ bnr_b, const float* __restrict__ bnr_m,
                                          const float* __restrict__ bnr_v,
                                          const float* __restrict__ bi,  const float* __restrict__ bni_g,
                                          const float* __restrict__ bni_b, const float* __restrict__ bni_m,
                                          const float* __restrict__ bni_v,
                                          const float* __restrict__ c,
                                          float* __restrict__ out) {
    const int b = blockIdx.x;
    const int conv = blockIdx.y;
    const int o = threadIdx.x;

    const float* bcp = conv ? bi    : br;
    const float* gp  = conv ? bni_g : bnr_g;
    const float* bbp = conv ? bni_b : bnr_b;
    const float* mp  = conv ? bni_m : bnr_m;
    const float* vp  = conv ? bni_v : bnr_v;

    const float sc = gp[o] * rsqrtf(vp[o] + EPSF);
    const float sh = (bcp[o] - mp[o]) * sc + bbp[o];

    const u16* P0 = P + ((size_t)((0 * 2 + conv) * 128 + b)) * 24576 + o;
    const u16* P1 = P + ((size_t)((1 * 2 + conv) * 128 + b)) * 24576 + o;
    const u16* zb = zpk + ((size_t)b * 384 + o) * 64;

    float sum = 0.f;
#pragma unroll 4
    for (int pix = 0; pix < 64; ++pix) {
        float cv = bf2f(P0[pix * 384]) + bf2f(P1[pix * 384]);
        float y = fmaf(cv, sc, sh);
        sum = fmaf(gelu_exact(y), bf2f(zb[pix]), sum);
    }

    __shared__ float red[6];
#pragma unroll
    for (int off = 32; off >= 1; off >>= 1) sum += __shfl_down(sum, off, 64);
    const int wv = o >> 6, ln = o & 63;
    if (ln == 0) red[wv] = sum;
    __syncthreads();
    if (o == 0) {
        float t = red[0] + red[1] + red[2] + red[3] + red[4] + red[5];
        out[conv * 128 + b] = 1.f / (1.f + expf(-t / c[0]));
    }
}

extern "C" void kernel_launch(void* const* d_in, const int* in_sizes, int n_in,
                              void* d_out, int out_size, void* d_ws, size_t ws_size,
                              hipStream_t stream) {
    const float* z_r   = (const float*)d_in[0];
    const float* z_i   = (const float*)d_in[1];
    const float* x_r   = (const float*)d_in[2];
    const float* x_i   = (const float*)d_in[3];
    const float* fz_w  = (const float*)d_in[4];
    const float* fz_b  = (const float*)d_in[5];
    const float* ln_g  = (const float*)d_in[6];
    const float* ln_b  = (const float*)d_in[7];
    const float* wr    = (const float*)d_in[8];
    const float* br    = (const float*)d_in[9];
    const float* bnr_g = (const float*)d_in[10];
    const float* bnr_b = (const float*)d_in[11];
    const float* bnr_m = (const float*)d_in[12];
    const float* bnr_v = (const float*)d_in[13];
    const float* wi    = (const float*)d_in[14];
    const float* bi    = (const float*)d_in[15];
    const float* bni_g = (const float*)d_in[16];
    const float* bni_b = (const float*)d_in[17];
    const float* bni_m = (const float*)d_in[18];
    const float* bni_v = (const float*)d_in[19];
    const float* c     = (const float*)d_in[20];

    // ws (bytes): Bz [0, 1179648) | Bw [+10616832) | zpk [+6291456) | P [+25165824)
    u16* Bz  = (u16*)d_ws;
    u16* Bw  = (u16*)((char*)d_ws + 1179648);
    u16* zpk = (u16*)((char*)d_ws + 1179648 + 10616832);
    u16* P   = (u16*)((char*)d_ws + 1179648 + 10616832 + 6291456);

    kprep_z<<<288, 256, 0, stream>>>(fz_w, Bz);
    kprep_w<<<768, 256, 0, stream>>>(wr, wi, Bw);
    kz2<<<dim3(2, 128), 384, 0, stream>>>(z_r, z_i, Bz, fz_b, ln_g, ln_b, zpk);
    kc17<<<dim3(4, 128), 768, 0, stream>>>(x_r, x_i, Bw, P);
    ke<<<dim3(128, 2), 384, 0, stream>>>(P, zpk,
                                         br, bnr_g, bnr_b, bnr_m, bnr_v,
                                         bi, bni_g, bni_b, bni_m, bni_v,
                                         c, (float*)d_out);
}

// Round 21
// 274.280 us; speedup vs baseline: 1.0646x; 1.0646x over previous
//
#include <hip/hip_runtime.h>
#include <hip/hip_bf16.h>
#include <math.h>

#define EPSF 1e-5f

typedef __bf16 v8bf __attribute__((ext_vector_type(8)));
typedef float  v4f  __attribute__((ext_vector_type(4)));
typedef unsigned int u32;
typedef unsigned short u16;

__device__ __forceinline__ float gelu_exact(float x) {
    return 0.5f * x * (1.0f + erff(x * 0.70710678f));
}
__device__ __forceinline__ u16 f2bf(float f) {   // RNE
    u32 u = __float_as_uint(f);
    return (u16)((u + 0x7fffu + ((u >> 16) & 1u)) >> 16);
}
__device__ __forceinline__ float bf2f(u16 u) {
    return __uint_as_float(((u32)u) << 16);
}
__device__ __forceinline__ void gload16(const void* g, void* l) {
    __builtin_amdgcn_global_load_lds((const __attribute__((address_space(1))) u32*)g,
                                     (__attribute__((address_space(3))) u32*)l, 16, 0, 0);
}

// counted-vmcnt barrier: allow N vector-mem ops outstanding, drain LDS ops.
#define BARRIER(N) do { \
    asm volatile("s_waitcnt vmcnt(" #N ") lgkmcnt(0)" ::: "memory"); \
    __builtin_amdgcn_s_barrier(); \
} while (0)

// ---------------------------------------------------------------------------
// Prep: fz_w[o][1536] f32 -> Bz[ec2][h][n][8] bf16 (coalesced reads)
// ---------------------------------------------------------------------------
__global__ __launch_bounds__(256) void kprep_z(const float* __restrict__ fz_w,
                                               u16* __restrict__ Bz) {
    int idx = blockIdx.x * 256 + threadIdx.x;   // 0 .. 73727
    int n = idx / 192;
    int r = idx % 192;
    int ec2 = r >> 2;
    int h = r & 3;
    const float* src = fz_w + (size_t)n * 1536 + ec2 * 32 + h * 8;
    float4 v0 = *(const float4*)src;
    float4 v1 = *(const float4*)(src + 4);
    uint4 pk;
    pk.x = (u32)f2bf(v0.x) | ((u32)f2bf(v0.y) << 16);
    pk.y = (u32)f2bf(v0.z) | ((u32)f2bf(v0.w) << 16);
    pk.z = (u32)f2bf(v1.x) | ((u32)f2bf(v1.y) << 16);
    pk.w = (u32)f2bf(v1.z) | ((u32)f2bf(v1.w) << 16);
    size_t slot = ((size_t)(ec2 * 4 + h) * 384 + n);
    *(uint4*)(Bz + slot * 8) = pk;
}

// ---------------------------------------------------------------------------
// Prep: w[n][e][3][3] f32 -> Bw[conv][s][ec2][h][n][8] bf16.
// ---------------------------------------------------------------------------
__global__ __launch_bounds__(256) void kprep_w(const float* __restrict__ wr,
                                               const float* __restrict__ wi,
                                               u16* __restrict__ Bw) {
    __shared__ float wsm[6912];
    const int tid = threadIdx.x;
    const int n = blockIdx.x >> 1;
    const int conv = blockIdx.x & 1;
    const float* w = (conv ? wi : wr) + (size_t)n * 6912;
#pragma unroll
    for (int k = 0; k < 7; ++k) {
        int sl = tid + k * 256;
        if (sl < 1728) ((float4*)wsm)[sl] = ((const float4*)w)[sl];
    }
    __syncthreads();
#pragma unroll
    for (int k = 0; k < 4; ++k) {
        int sl = tid + k * 256;          // (s*24+ec2)*4 + h
        if (sl < 864) {
            int h = sl & 3;
            int r = sl >> 2;
            int ec2 = r % 24;
            int s = r / 24;
            int ch0 = ec2 * 32 + h * 8;
            u16 tmp[8];
#pragma unroll
            for (int e = 0; e < 8; ++e) tmp[e] = f2bf(wsm[(ch0 + e) * 9 + s]);
            uint4 pk;
            pk.x = (u32)tmp[0] | ((u32)tmp[1] << 16);
            pk.y = (u32)tmp[2] | ((u32)tmp[3] << 16);
            pk.z = (u32)tmp[4] | ((u32)tmp[5] << 16);
            pk.w = (u32)tmp[6] | ((u32)tmp[7] << 16);
            size_t slot = ((size_t)conv * 864 + sl) * 384 + n;
            *(uint4*)(Bw + slot * 8) = pk;
        }
    }
}

// ---------------------------------------------------------------------------
// kz2: z = gelu(LN(concat(z_r,z_i) @ fz_w^T + fz_b)) via MFMA.
// grid (2 t-halves, 128 b), 384 thr = 6 waves. Writes zpk[b][o][t(64)] bf16.
// ---------------------------------------------------------------------------
#define ZB_BUF 24576
#define ZA_BUF 2048

__global__ __launch_bounds__(384, 1) void kz2(const float* __restrict__ z_r,
                                              const float* __restrict__ z_i,
                                              const u16* __restrict__ Bz,
                                              const float* __restrict__ fz_b,
                                              const float* __restrict__ ln_g,
                                              const float* __restrict__ ln_b,
                                              u16* __restrict__ zpk) {
    const int th = blockIdx.x;
    const int b  = blockIdx.y;
    const int tid  = threadIdx.x;
    const int lane = tid & 63;
    const int wid  = tid >> 6;
    const int l15  = lane & 15;
    const int h    = lane >> 4;

    __shared__ __align__(16) char lds[3 * ZB_BUF + 2 * ZA_BUF];   // 77824
    char* ldsZB = lds;
    char* ldsZA = lds + 3 * ZB_BUF;
    __shared__ float redS[6 * 32], redQ[6 * 32], mu_s[32], rs_s[32];

    const float* zr_b = z_r + (size_t)b * (64 * 768);
    const float* zi_b = z_i + (size_t)b * (64 * 768);

    int boff[4];
#pragma unroll
    for (int nj = 0; nj < 4; ++nj) {
        int n = wid * 64 + nj * 16 + l15;
        boff[nj] = h * 6144 + n * 16;
    }
    int zaoff[2];
#pragma unroll
    for (int mi = 0; mi < 2; ++mi)
        zaoff[mi] = h * 512 + (mi * 16 + l15) * 16;

    auto stageZB = [&](int ec2, char* buf) {       // 4 gload16 / thread
        const char* src = (const char*)(Bz + (size_t)ec2 * 1536 * 8);
#pragma unroll
        for (int k = 0; k < 4; ++k) {
            int sl = tid + k * 384;
            gload16(src + sl * 16, buf + sl * 16);
        }
    };
    auto issueZA = [&](int ec2, float4* zr) {      // 1 load / thread (uniform)
        const float* zsrc = (ec2 < 24) ? zr_b : zi_b;
        const int ch0 = (ec2 < 24 ? ec2 : ec2 - 24) * 32;
        int sl = tid & 255;
        int row = sl >> 3, qq = sl & 7;
        zr[0] = *(const float4*)(zsrc + (size_t)(th * 32 + row) * 768 + ch0 + qq * 4);
    };
    auto convertZA = [&](const float4* zr, char* buf) {
        int sl = tid & 255;
        int row = sl >> 3, qq = sl & 7;
        ushort4 pk;
        pk.x = f2bf(zr[0].x); pk.y = f2bf(zr[0].y);
        pk.z = f2bf(zr[0].z); pk.w = f2bf(zr[0].w);
        *(ushort4*)(buf + (qq >> 1) * 512 + row * 16 + (qq & 1) * 8) = pk;
    };

    v4f acc[2][4] = {};

    auto comp = [&](char* curA, char* curB) {
        v8bf a[2], bfv[4];
#pragma unroll
        for (int mi = 0; mi < 2; ++mi) a[mi] = *(const v8bf*)(curA + zaoff[mi]);
#pragma unroll
        for (int nj = 0; nj < 4; ++nj) bfv[nj] = *(const v8bf*)(curB + boff[nj]);
        __builtin_amdgcn_s_setprio(1);
#pragma unroll
        for (int mi = 0; mi < 2; ++mi)
#pragma unroll
            for (int nj = 0; nj < 4; ++nj)
                acc[mi][nj] = __builtin_amdgcn_mfma_f32_16x16x32_bf16(a[mi], bfv[nj], acc[mi][nj], 0, 0, 0);
        __builtin_amdgcn_s_setprio(0);
    };

    float4 zreg[1];
    {
        issueZA(0, zreg);
        stageZB(0, ldsZB);
        stageZB(1, ldsZB + ZB_BUF);
        convertZA(zreg, ldsZA);      // waits ZA(0)
        issueZA(1, zreg);
        BARRIER(5);                  // allow ZB(1)=4 + ZA(1)=1
    }
#pragma unroll 1
    for (int t = 0; t < 46; ++t) {
        stageZB(t + 2, ldsZB + ((t + 2) % 3) * ZB_BUF);
        comp(ldsZA + (t & 1) * ZA_BUF, ldsZB + (t % 3) * ZB_BUF);
        convertZA(zreg, ldsZA + ((t + 1) & 1) * ZA_BUF);  // waits ZA(t+1): vmcnt(4)
        issueZA(t + 2, zreg);
        BARRIER(5);                  // allow ZB(t+2)=4 + ZA(t+2)=1; drains ZB(t+1)
    }
    {   // t = 46
        comp(ldsZA + (46 & 1) * ZA_BUF, ldsZB + (46 % 3) * ZB_BUF);
        convertZA(zreg, ldsZA + (47 & 1) * ZA_BUF);       // waits ZA(47): vmcnt(0)
        BARRIER(0);
    }
    comp(ldsZA + (47 & 1) * ZA_BUF, ldsZB + (47 % 3) * ZB_BUF);

    // ---- bias + LN stats (rows 0..31 local) ----
    float fzb[4], lng[4], lnb[4];
#pragma unroll
    for (int nj = 0; nj < 4; ++nj) {
        int o = wid * 64 + nj * 16 + l15;
        fzb[nj] = fz_b[o]; lng[nj] = ln_g[o]; lnb[nj] = ln_b[o];
    }
#pragma unroll
    for (int mi = 0; mi < 2; ++mi)
#pragma unroll
        for (int nj = 0; nj < 4; ++nj)
#pragma unroll
            for (int reg = 0; reg < 4; ++reg)
                acc[mi][nj][reg] += fzb[nj];

#pragma unroll
    for (int mi = 0; mi < 2; ++mi) {
#pragma unroll
        for (int reg = 0; reg < 4; ++reg) {
            float s = 0.f, q = 0.f;
#pragma unroll
            for (int nj = 0; nj < 4; ++nj) {
                float v = acc[mi][nj][reg];
                s += v; q += v * v;
            }
#pragma unroll
            for (int m = 0; m < 4; ++m) {
                s += __shfl_xor(s, 1 << m, 64);
                q += __shfl_xor(q, 1 << m, 64);
            }
            if (l15 == 0) {
                int row = mi * 16 + h * 4 + reg;
                redS[wid * 32 + row] = s;
                redQ[wid * 32 + row] = q;
            }
        }
    }
    __syncthreads();
    if (tid < 32) {
        float s = 0.f, q = 0.f;
#pragma unroll
        for (int w6 = 0; w6 < 6; ++w6) { s += redS[w6 * 32 + tid]; q += redQ[w6 * 32 + tid]; }
        float mu = s * (1.0f / 384.0f);
        float var = q * (1.0f / 384.0f) - mu * mu;
        mu_s[tid] = mu;
        rs_s[tid] = rsqrtf(var + EPSF);
    }
    __syncthreads();

    // ---- LN + gelu -> zpk[b][o][t] ----
#pragma unroll
    for (int mi = 0; mi < 2; ++mi)
#pragma unroll
        for (int nj = 0; nj < 4; ++nj) {
            int o = wid * 64 + nj * 16 + l15;
            u32* dst = (u32*)zpk + ((size_t)b * 384 + o) * 32 + th * 16 + mi * 8 + h * 2;
#pragma unroll
            for (int rp = 0; rp < 2; ++rp) {
                float zv[2];
#pragma unroll
                for (int k = 0; k < 2; ++k) {
                    int reg = rp * 2 + k;
                    int row = mi * 16 + h * 4 + reg;
                    float v = (acc[mi][nj][reg] - mu_s[row]) * rs_s[row] * lng[nj] + lnb[nj];
                    zv[k] = gelu_exact(v);
                }
                dst[rp] = (u32)f2bf(zv[0]) | ((u32)f2bf(zv[1]) << 16);
            }
        }
}

// ---------------------------------------------------------------------------
// kc17b: kc14 body, K-split across blocks, FRAGMENT-DUMP stores (coalesced).
// block = (kh, conv, b); 12 ec2 each. 768 thr = 12 waves, wave tile 64x32.
// grid 512 = 2 blocks/CU = 24 waves/CU. Stores packed u32 (2 bf16) at
// P[q][b][frag][lane] -- every wave store is 256B contiguous.
// ---------------------------------------------------------------------------
#define APL14  2816            // A h-plane stride (176*16)
#define ABUF14 (4 * APL14)     // 11264 per ec2 buffer
#define SSTR14 589824          // 24 * 24576 : tap-s stride in Bw
#define ESTR14 24576           // ec2 stride in Bw

__global__ __launch_bounds__(768, 6) void kc17b(const float* __restrict__ x_r,
                                                const float* __restrict__ x_i,
                                                const u16* __restrict__ Bw,
                                                u32* __restrict__ P) {
    const int q    = blockIdx.x;        // kh*2 + conv
    const int kh   = q >> 1;
    const int conv = q & 1;
    const int b    = blockIdx.y;
    const int tid  = threadIdx.x;
    const int lane = tid & 63;
    const int wid  = tid >> 6;          // 0..11 = 32-col group
    const int l15  = lane & 15;
    const int h    = lane >> 4;         // 0..3
    const int e0   = kh * 12;

    __shared__ __align__(16) char ldsA[2 * ABUF14];   // 22528

    const float* x  = conv ? x_i : x_r;
    const float* xb = x + (size_t)b * (256 * 768);

    const char* bbase = (const char*)(Bw + (size_t)conv * (864 * 384 * 8))
                      + (size_t)h * 6144 + (wid * 32 + l15) * 16;

    int aoff[4];
#pragma unroll
    for (int mi = 0; mi < 4; ++mi) {
        int p = mi * 16 + l15;
        int i = p >> 3, j = p & 7;
        aoff[mi] = h * APL14 + (i * 16 + j + 3) * 16;
    }

    auto issueA = [&](int ec2, float4* ar) {          // 2 loads/thread (wrapped dup)
#pragma unroll
        for (int k = 0; k < 2; ++k) {
            int sl = tid + k * 768;
            if (sl >= 1408) sl -= 1408;
            int row = sl >> 3, qq = sl & 7;
            ar[k] = *(const float4*)(xb + (size_t)(48 + row) * 768 + ec2 * 32 + qq * 4);
        }
    };
    auto convertA = [&](const float4* ar, char* buf) {
#pragma unroll
        for (int k = 0; k < 2; ++k) {
            int sl = tid + k * 768;
            if (sl >= 1408) sl -= 1408;
            int row = sl >> 3, qq = sl & 7;
            ushort4 pk;
            pk.x = f2bf(ar[k].x); pk.y = f2bf(ar[k].y);
            pk.z = f2bf(ar[k].z); pk.w = f2bf(ar[k].w);
            *(ushort4*)(buf + (qq >> 1) * APL14 + row * 16 + (qq & 1) * 8) = pk;
        }
    };

    v4f acc[4][2] = {};
    v8bf bpipe[3][2];
    float4 areg[2];

    {   // prologue: A(e0) issued first (oldest), then 6 B loads (taps 0..2)
        issueA(e0, areg);
#pragma unroll
        for (int i = 0; i < 3; ++i) {
            const char* p = bbase + (size_t)e0 * ESTR14 + (size_t)i * SSTR14;
            bpipe[i][0] = *(const v8bf*)p;
            bpipe[i][1] = *(const v8bf*)(p + 256);
        }
        convertA(areg, ldsA);        // reg-dep drains areg (vmcnt<=6); bpipe stays
        BARRIER(6);                  // all 6 B prefetches remain in flight
    }

    // TAP(S): compute tap (e,S); prefetch tap (9e+S+3)'s 2 B frags.
#define TAP(S) do { \
        v8bf b0 = bpipe[(S) % 3][0]; \
        v8bf b1 = bpipe[(S) % 3][1]; \
        const int _so = (((S) / 3) * 16 + ((S) % 3)) * 16; \
        v8bf a0 = *(const v8bf*)(Acur + aoff[0] + _so); \
        v8bf a1 = *(const v8bf*)(Acur + aoff[1] + _so); \
        v8bf a2 = *(const v8bf*)(Acur + aoff[2] + _so); \
        v8bf a3 = *(const v8bf*)(Acur + aoff[3] + _so); \
        __builtin_amdgcn_s_setprio(1); \
        acc[0][0] = __builtin_amdgcn_mfma_f32_16x16x32_bf16(a0, b0, acc[0][0], 0, 0, 0); \
        acc[0][1] = __builtin_amdgcn_mfma_f32_16x16x32_bf16(a0, b1, acc[0][1], 0, 0, 0); \
        acc[1][0] = __builtin_amdgcn_mfma_f32_16x16x32_bf16(a1, b0, acc[1][0], 0, 0, 0); \
        acc[1][1] = __builtin_amdgcn_mfma_f32_16x16x32_bf16(a1, b1, acc[1][1], 0, 0, 0); \
        acc[2][0] = __builtin_amdgcn_mfma_f32_16x16x32_bf16(a2, b0, acc[2][0], 0, 0, 0); \
        acc[2][1] = __builtin_amdgcn_mfma_f32_16x16x32_bf16(a2, b1, acc[2][1], 0, 0, 0); \
        acc[3][0] = __builtin_amdgcn_mfma_f32_16x16x32_bf16(a3, b0, acc[3][0], 0, 0, 0); \
        acc[3][1] = __builtin_amdgcn_mfma_f32_16x16x32_bf16(a3, b1, acc[3][1], 0, 0, 0); \
        __builtin_amdgcn_s_setprio(0); \
        if ((S) <= 5) { \
            const char* _p = bptr + (size_t)((S) + 3) * SSTR14; \
            bpipe[(S) % 3][0] = *(const v8bf*)_p; \
            bpipe[(S) % 3][1] = *(const v8bf*)(_p + 256); \
        } else if (e < e0 + 11) { \
            const char* _p = bptr + ESTR14 + (size_t)((S) - 6) * SSTR14; \
            bpipe[(S) % 3][0] = *(const v8bf*)_p; \
            bpipe[(S) % 3][1] = *(const v8bf*)(_p + 256); \
        } \
    } while (0)

#pragma unroll 1
    for (int e = e0; e < e0 + 12; ++e) {
        const char* Acur = ldsA + (e & 1) * ABUF14;
        const char* bptr = bbase + (size_t)e * ESTR14;
        TAP(0); TAP(1); TAP(2);
        if (e < e0 + 11) issueA(e + 1, areg);
        TAP(3); TAP(4); TAP(5); TAP(6);
        if (e < e0 + 11) convertA(areg, ldsA + ((e + 1) & 1) * ABUF14);  // drains areg
        TAP(7); TAP(8);
        if (e < e0 + 11) BARRIER(6);     // 6 next-ec2 B prefetches stay in flight
    }
#undef TAP

    // ---- fragment-dump store: fully coalesced 256B wave stores ----
    u32* Pd = P + ((size_t)(q * 128 + b)) * 12288;
#pragma unroll
    for (int nj = 0; nj < 2; ++nj)
#pragma unroll
        for (int mi = 0; mi < 4; ++mi)
#pragma unroll
            for (int rp = 0; rp < 2; ++rp) {
                u32 pk = (u32)f2bf(acc[mi][nj][rp * 2]) |
                         ((u32)f2bf(acc[mi][nj][rp * 2 + 1]) << 16);
                Pd[((((size_t)wid * 2 + nj) * 4 + mi) * 2 + rp) * 64 + lane] = pk;
            }
}

// ---------------------------------------------------------------------------
// ke2: merge K-halves (fragment order), BN + gelu + dot(zpk) + sigmoid.
// grid (128 b, 2 conv), 768 thr mirroring kc17b's fragment geometry.
// ---------------------------------------------------------------------------
__global__ __launch_bounds__(768) void ke2(const u32* __restrict__ P,
                                           const u16* __restrict__ zpk,
                                           const float* __restrict__ br,  const float* __restrict__ bnr_g,
                                           const float* __restrict__ bnr_b, const float* __restrict__ bnr_m,
                                           const float* __restrict__ bnr_v,
                                           const float* __restrict__ bi,  const float* __restrict__ bni_g,
                                           const float* __restrict__ bni_b, const float* __restrict__ bni_m,
                                           const float* __restrict__ bni_v,
                                           const float* __restrict__ c,
                                           float* __restrict__ out) {
    const int b    = blockIdx.x;
    const int conv = blockIdx.y;
    const int tid  = threadIdx.x;
    const int lane = tid & 63;
    const int wid  = tid >> 6;          // 0..11
    const int l15  = lane & 15;
    const int h    = lane >> 4;

    const float* bcp = conv ? bi    : br;
    const float* gp  = conv ? bni_g : bnr_g;
    const float* bbp = conv ? bni_b : bnr_b;
    const float* mp  = conv ? bni_m : bnr_m;
    const float* vp  = conv ? bni_v : bnr_v;

    const u32* P0 = P + ((size_t)(conv * 128 + b)) * 12288;
    const u32* P1 = P + ((size_t)((2 + conv) * 128 + b)) * 12288;

    float sum = 0.f;
#pragma unroll
    for (int nj = 0; nj < 2; ++nj) {
        const int o = wid * 32 + nj * 16 + l15;
        const float sc  = gp[o] * rsqrtf(vp[o] + EPSF);
        const float sh2 = (bcp[o] - mp[o]) * sc + bbp[o];
        const u16* zb = zpk + ((size_t)b * 384 + o) * 64;
#pragma unroll
        for (int mi = 0; mi < 4; ++mi) {
            ushort4 zw = *(const ushort4*)(zb + mi * 16 + h * 4);
#pragma unroll
            for (int rp = 0; rp < 2; ++rp) {
                size_t idx = ((((size_t)wid * 2 + nj) * 4 + mi) * 2 + rp) * 64 + lane;
                u32 a0 = P0[idx], a1 = P1[idx];
#pragma unroll
                for (int k = 0; k < 2; ++k) {
                    int reg = rp * 2 + k;
                    float cv = bf2f((u16)(k ? (a0 >> 16) : (a0 & 0xffff)))
                             + bf2f((u16)(k ? (a1 >> 16) : (a1 & 0xffff)));
                    float y = fmaf(cv, sc, sh2);
                    u16 zu = (reg == 0) ? zw.x : (reg == 1) ? zw.y : (reg == 2) ? zw.z : zw.w;
                    sum = fmaf(gelu_exact(y), bf2f(zu), sum);
                }
            }
        }
    }
#pragma unroll
    for (int off = 32; off >= 1; off >>= 1) sum += __shfl_down(sum, off, 64);

    __shared__ float redF[12];
    if (lane == 0) redF[wid] = sum;
    __syncthreads();
    if (tid == 0) {
        float t = 0.f;
#pragma unroll
        for (int w12 = 0; w12 < 12; ++w12) t += redF[w12];
        out[conv * 128 + b] = 1.f / (1.f + expf(-t / c[0]));
    }
}

extern "C" void kernel_launch(void* const* d_in, const int* in_sizes, int n_in,
                              void* d_out, int out_size, void* d_ws, size_t ws_size,
                              hipStream_t stream) {
    const float* z_r   = (const float*)d_in[0];
    const float* z_i   = (const float*)d_in[1];
    const float* x_r   = (const float*)d_in[2];
    const float* x_i   = (const float*)d_in[3];
    const float* fz_w  = (const float*)d_in[4];
    const float* fz_b  = (const float*)d_in[5];
    const float* ln_g  = (const float*)d_in[6];
    const float* ln_b  = (const float*)d_in[7];
    const float* wr    = (const float*)d_in[8];
    const float* br    = (const float*)d_in[9];
    const float* bnr_g = (const float*)d_in[10];
    const float* bnr_b = (const float*)d_in[11];
    const float* bnr_m = (const float*)d_in[12];
    const float* bnr_v = (const float*)d_in[13];
    const float* wi    = (const float*)d_in[14];
    const float* bi    = (const float*)d_in[15];
    const float* bni_g = (const float*)d_in[16];
    const float* bni_b = (const float*)d_in[17];
    const float* bni_m = (const float*)d_in[18];
    const float* bni_v = (const float*)d_in[19];
    const float* c     = (const float*)d_in[20];

    // ws (bytes): Bz [0, 1179648) | Bw [+10616832) | zpk [+6291456) | P [+25165824)
    u16* Bz  = (u16*)d_ws;
    u16* Bw  = (u16*)((char*)d_ws + 1179648);
    u16* zpk = (u16*)((char*)d_ws + 1179648 + 10616832);
    u32* P   = (u32*)((char*)d_ws + 1179648 + 10616832 + 6291456);

    kprep_z<<<288, 256, 0, stream>>>(fz_w, Bz);
    kprep_w<<<768, 256, 0, stream>>>(wr, wi, Bw);
    kz2<<<dim3(2, 128), 384, 0, stream>>>(z_r, z_i, Bz, fz_b, ln_g, ln_b, zpk);
    kc17b<<<dim3(4, 128), 768, 0, stream>>>(x_r, x_i, Bw, P);
    ke2<<<dim3(128, 2), 768, 0, stream>>>(P, zpk,
                                          br, bnr_g, bnr_b, bnr_m, bnr_v,
                                          bi, bni_g, bni_b, bni_m, bni_v,
                                          c, (float*)d_out);
}

// Round 22
// 173.115 us; speedup vs baseline: 1.6867x; 1.5844x over previous
//
#include <hip/hip_runtime.h>
#include <hip/hip_bf16.h>
#include <math.h>

#define EPSF 1e-5f

typedef __bf16 v8bf __attribute__((ext_vector_type(8)));
typedef float  v4f  __attribute__((ext_vector_type(4)));
typedef unsigned int u32;
typedef unsigned short u16;

__device__ __forceinline__ float gelu_exact(float x) {
    return 0.5f * x * (1.0f + erff(x * 0.70710678f));
}
__device__ __forceinline__ u16 f2bf(float f) {   // RNE
    u32 u = __float_as_uint(f);
    return (u16)((u + 0x7fffu + ((u >> 16) & 1u)) >> 16);
}
__device__ __forceinline__ float bf2f(u16 u) {
    return __uint_as_float(((u32)u) << 16);
}
__device__ __forceinline__ void gload16(const void* g, void* l) {
    __builtin_amdgcn_global_load_lds((const __attribute__((address_space(1))) u32*)g,
                                     (__attribute__((address_space(3))) u32*)l, 16, 0, 0);
}

// counted-vmcnt barrier: allow N vector-mem ops outstanding, drain LDS ops.
#define BARRIER(N) do { \
    asm volatile("s_waitcnt vmcnt(" #N ") lgkmcnt(0)" ::: "memory"); \
    __builtin_amdgcn_s_barrier(); \
} while (0)

// ---------------------------------------------------------------------------
// Prep: fz_w[o][1536] f32 -> Bz[ec2][h][n][8] bf16 (coalesced reads)
// ---------------------------------------------------------------------------
__global__ __launch_bounds__(256) void kprep_z(const float* __restrict__ fz_w,
                                               u16* __restrict__ Bz) {
    int idx = blockIdx.x * 256 + threadIdx.x;   // 0 .. 73727
    int n = idx / 192;
    int r = idx % 192;
    int ec2 = r >> 2;
    int h = r & 3;
    const float* src = fz_w + (size_t)n * 1536 + ec2 * 32 + h * 8;
    float4 v0 = *(const float4*)src;
    float4 v1 = *(const float4*)(src + 4);
    uint4 pk;
    pk.x = (u32)f2bf(v0.x) | ((u32)f2bf(v0.y) << 16);
    pk.y = (u32)f2bf(v0.z) | ((u32)f2bf(v0.w) << 16);
    pk.z = (u32)f2bf(v1.x) | ((u32)f2bf(v1.y) << 16);
    pk.w = (u32)f2bf(v1.z) | ((u32)f2bf(v1.w) << 16);
    size_t slot = ((size_t)(ec2 * 4 + h) * 384 + n);
    *(uint4*)(Bz + slot * 8) = pk;
}

// ---------------------------------------------------------------------------
// Prep: w[n][e][3][3] f32 -> Bw[conv][s][ec2][h][n][8] bf16.
// ---------------------------------------------------------------------------
__global__ __launch_bounds__(256) void kprep_w(const float* __restrict__ wr,
                                               const float* __restrict__ wi,
                                               u16* __restrict__ Bw) {
    __shared__ float wsm[6912];
    const int tid = threadIdx.x;
    const int n = blockIdx.x >> 1;
    const int conv = blockIdx.x & 1;
    const float* w = (conv ? wi : wr) + (size_t)n * 6912;
#pragma unroll
    for (int k = 0; k < 7; ++k) {
        int sl = tid + k * 256;
        if (sl < 1728) ((float4*)wsm)[sl] = ((const float4*)w)[sl];
    }
    __syncthreads();
#pragma unroll
    for (int k = 0; k < 4; ++k) {
        int sl = tid + k * 256;          // (s*24+ec2)*4 + h
        if (sl < 864) {
            int h = sl & 3;
            int r = sl >> 2;
            int ec2 = r % 24;
            int s = r / 24;
            int ch0 = ec2 * 32 + h * 8;
            u16 tmp[8];
#pragma unroll
            for (int e = 0; e < 8; ++e) tmp[e] = f2bf(wsm[(ch0 + e) * 9 + s]);
            uint4 pk;
            pk.x = (u32)tmp[0] | ((u32)tmp[1] << 16);
            pk.y = (u32)tmp[2] | ((u32)tmp[3] << 16);
            pk.z = (u32)tmp[4] | ((u32)tmp[5] << 16);
            pk.w = (u32)tmp[6] | ((u32)tmp[7] << 16);
            size_t slot = ((size_t)conv * 864 + sl) * 384 + n;
            *(uint4*)(Bw + slot * 8) = pk;
        }
    }
}

// ---------------------------------------------------------------------------
// kz2: z = gelu(LN(concat(z_r,z_i) @ fz_w^T + fz_b)) via MFMA.
// grid (2 t-halves, 128 b), 384 thr = 6 waves. Writes zpk[b][o][t(64)] bf16.
// ---------------------------------------------------------------------------
#define ZB_BUF 24576
#define ZA_BUF 2048

__global__ __launch_bounds__(384, 1) void kz2(const float* __restrict__ z_r,
                                              const float* __restrict__ z_i,
                                              const u16* __restrict__ Bz,
                                              const float* __restrict__ fz_b,
                                              const float* __restrict__ ln_g,
                                              const float* __restrict__ ln_b,
                                              u16* __restrict__ zpk) {
    const int th = blockIdx.x;
    const int b  = blockIdx.y;
    const int tid  = threadIdx.x;
    const int lane = tid & 63;
    const int wid  = tid >> 6;
    const int l15  = lane & 15;
    const int h    = lane >> 4;

    __shared__ __align__(16) char lds[3 * ZB_BUF + 2 * ZA_BUF];   // 77824
    char* ldsZB = lds;
    char* ldsZA = lds + 3 * ZB_BUF;
    __shared__ float redS[6 * 32], redQ[6 * 32], mu_s[32], rs_s[32];

    const float* zr_b = z_r + (size_t)b * (64 * 768);
    const float* zi_b = z_i + (size_t)b * (64 * 768);

    int boff[4];
#pragma unroll
    for (int nj = 0; nj < 4; ++nj) {
        int n = wid * 64 + nj * 16 + l15;
        boff[nj] = h * 6144 + n * 16;
    }
    int zaoff[2];
#pragma unroll
    for (int mi = 0; mi < 2; ++mi)
        zaoff[mi] = h * 512 + (mi * 16 + l15) * 16;

    auto stageZB = [&](int ec2, char* buf) {       // 4 gload16 / thread
        const char* src = (const char*)(Bz + (size_t)ec2 * 1536 * 8);
#pragma unroll
        for (int k = 0; k < 4; ++k) {
            int sl = tid + k * 384;
            gload16(src + sl * 16, buf + sl * 16);
        }
    };
    auto issueZA = [&](int ec2, float4* zr) {      // 1 load / thread (uniform)
        const float* zsrc = (ec2 < 24) ? zr_b : zi_b;
        const int ch0 = (ec2 < 24 ? ec2 : ec2 - 24) * 32;
        int sl = tid & 255;
        int row = sl >> 3, qq = sl & 7;
        zr[0] = *(const float4*)(zsrc + (size_t)(th * 32 + row) * 768 + ch0 + qq * 4);
    };
    auto convertZA = [&](const float4* zr, char* buf) {
        int sl = tid & 255;
        int row = sl >> 3, qq = sl & 7;
        ushort4 pk;
        pk.x = f2bf(zr[0].x); pk.y = f2bf(zr[0].y);
        pk.z = f2bf(zr[0].z); pk.w = f2bf(zr[0].w);
        *(ushort4*)(buf + (qq >> 1) * 512 + row * 16 + (qq & 1) * 8) = pk;
    };

    v4f acc[2][4] = {};

    auto comp = [&](char* curA, char* curB) {
        v8bf a[2], bfv[4];
#pragma unroll
        for (int mi = 0; mi < 2; ++mi) a[mi] = *(const v8bf*)(curA + zaoff[mi]);
#pragma unroll
        for (int nj = 0; nj < 4; ++nj) bfv[nj] = *(const v8bf*)(curB + boff[nj]);
        __builtin_amdgcn_s_setprio(1);
#pragma unroll
        for (int mi = 0; mi < 2; ++mi)
#pragma unroll
            for (int nj = 0; nj < 4; ++nj)
                acc[mi][nj] = __builtin_amdgcn_mfma_f32_16x16x32_bf16(a[mi], bfv[nj], acc[mi][nj], 0, 0, 0);
        __builtin_amdgcn_s_setprio(0);
    };

    float4 zreg[1];
    {
        issueZA(0, zreg);
        stageZB(0, ldsZB);
        stageZB(1, ldsZB + ZB_BUF);
        convertZA(zreg, ldsZA);      // waits ZA(0)
        issueZA(1, zreg);
        BARRIER(5);                  // allow ZB(1)=4 + ZA(1)=1
    }
#pragma unroll 1
    for (int t = 0; t < 46; ++t) {
        stageZB(t + 2, ldsZB + ((t + 2) % 3) * ZB_BUF);
        comp(ldsZA + (t & 1) * ZA_BUF, ldsZB + (t % 3) * ZB_BUF);
        convertZA(zreg, ldsZA + ((t + 1) & 1) * ZA_BUF);  // waits ZA(t+1): vmcnt(4)
        issueZA(t + 2, zreg);
        BARRIER(5);                  // allow ZB(t+2)=4 + ZA(t+2)=1; drains ZB(t+1)
    }
    {   // t = 46
        comp(ldsZA + (46 & 1) * ZA_BUF, ldsZB + (46 % 3) * ZB_BUF);
        convertZA(zreg, ldsZA + (47 & 1) * ZA_BUF);       // waits ZA(47): vmcnt(0)
        BARRIER(0);
    }
    comp(ldsZA + (47 & 1) * ZA_BUF, ldsZB + (47 % 3) * ZB_BUF);

    // ---- bias + LN stats (rows 0..31 local) ----
    float fzb[4], lng[4], lnb[4];
#pragma unroll
    for (int nj = 0; nj < 4; ++nj) {
        int o = wid * 64 + nj * 16 + l15;
        fzb[nj] = fz_b[o]; lng[nj] = ln_g[o]; lnb[nj] = ln_b[o];
    }
#pragma unroll
    for (int mi = 0; mi < 2; ++mi)
#pragma unroll
        for (int nj = 0; nj < 4; ++nj)
#pragma unroll
            for (int reg = 0; reg < 4; ++reg)
                acc[mi][nj][reg] += fzb[nj];

#pragma unroll
    for (int mi = 0; mi < 2; ++mi) {
#pragma unroll
        for (int reg = 0; reg < 4; ++reg) {
            float s = 0.f, q = 0.f;
#pragma unroll
            for (int nj = 0; nj < 4; ++nj) {
                float v = acc[mi][nj][reg];
                s += v; q += v * v;
            }
#pragma unroll
            for (int m = 0; m < 4; ++m) {
                s += __shfl_xor(s, 1 << m, 64);
                q += __shfl_xor(q, 1 << m, 64);
            }
            if (l15 == 0) {
                int row = mi * 16 + h * 4 + reg;
                redS[wid * 32 + row] = s;
                redQ[wid * 32 + row] = q;
            }
        }
    }
    __syncthreads();
    if (tid < 32) {
        float s = 0.f, q = 0.f;
#pragma unroll
        for (int w6 = 0; w6 < 6; ++w6) { s += redS[w6 * 32 + tid]; q += redQ[w6 * 32 + tid]; }
        float mu = s * (1.0f / 384.0f);
        float var = q * (1.0f / 384.0f) - mu * mu;
        mu_s[tid] = mu;
        rs_s[tid] = rsqrtf(var + EPSF);
    }
    __syncthreads();

    // ---- LN + gelu -> zpk[b][o][t] ----
#pragma unroll
    for (int mi = 0; mi < 2; ++mi)
#pragma unroll
        for (int nj = 0; nj < 4; ++nj) {
            int o = wid * 64 + nj * 16 + l15;
            u32* dst = (u32*)zpk + ((size_t)b * 384 + o) * 32 + th * 16 + mi * 8 + h * 2;
#pragma unroll
            for (int rp = 0; rp < 2; ++rp) {
                float zv[2];
#pragma unroll
                for (int k = 0; k < 2; ++k) {
                    int reg = rp * 2 + k;
                    int row = mi * 16 + h * 4 + reg;
                    float v = (acc[mi][nj][reg] - mu_s[row]) * rs_s[row] * lng[nj] + lnb[nj];
                    zv[k] = gelu_exact(v);
                }
                dst[rp] = (u32)f2bf(zv[0]) | ((u32)f2bf(zv[1]) << 16);
            }
        }
}

// ---------------------------------------------------------------------------
// kc17c: kc17b with __launch_bounds__(768,3) -- no forced VGPR cap, no spill.
// K-split across blocks; block = (kh, conv, b); 12 ec2 each. 768 thr = 12
// waves, wave tile 64x32. grid 512; 2 blocks/CU at runtime if VGPR<=64.
// Fragment-dump stores (coalesced 256B wave stores).
// ---------------------------------------------------------------------------
#define APL14  2816            // A h-plane stride (176*16)
#define ABUF14 (4 * APL14)     // 11264 per ec2 buffer
#define SSTR14 589824          // 24 * 24576 : tap-s stride in Bw
#define ESTR14 24576           // ec2 stride in Bw

__global__ __launch_bounds__(768, 3) void kc17c(const float* __restrict__ x_r,
                                                const float* __restrict__ x_i,
                                                const u16* __restrict__ Bw,
                                                u32* __restrict__ P) {
    const int q    = blockIdx.x;        // kh*2 + conv
    const int kh   = q >> 1;
    const int conv = q & 1;
    const int b    = blockIdx.y;
    const int tid  = threadIdx.x;
    const int lane = tid & 63;
    const int wid  = tid >> 6;          // 0..11 = 32-col group
    const int l15  = lane & 15;
    const int h    = lane >> 4;         // 0..3
    const int e0   = kh * 12;

    __shared__ __align__(16) char ldsA[2 * ABUF14];   // 22528

    const float* x  = conv ? x_i : x_r;
    const float* xb = x + (size_t)b * (256 * 768);

    const char* bbase = (const char*)(Bw + (size_t)conv * (864 * 384 * 8))
                      + (size_t)h * 6144 + (wid * 32 + l15) * 16;

    int aoff[4];
#pragma unroll
    for (int mi = 0; mi < 4; ++mi) {
        int p = mi * 16 + l15;
        int i = p >> 3, j = p & 7;
        aoff[mi] = h * APL14 + (i * 16 + j + 3) * 16;
    }

    auto issueA = [&](int ec2, float4* ar) {          // 2 loads/thread (wrapped dup)
#pragma unroll
        for (int k = 0; k < 2; ++k) {
            int sl = tid + k * 768;
            if (sl >= 1408) sl -= 1408;
            int row = sl >> 3, qq = sl & 7;
            ar[k] = *(const float4*)(xb + (size_t)(48 + row) * 768 + ec2 * 32 + qq * 4);
        }
    };
    auto convertA = [&](const float4* ar, char* buf) {
#pragma unroll
        for (int k = 0; k < 2; ++k) {
            int sl = tid + k * 768;
            if (sl >= 1408) sl -= 1408;
            int row = sl >> 3, qq = sl & 7;
            ushort4 pk;
            pk.x = f2bf(ar[k].x); pk.y = f2bf(ar[k].y);
            pk.z = f2bf(ar[k].z); pk.w = f2bf(ar[k].w);
            *(ushort4*)(buf + (qq >> 1) * APL14 + row * 16 + (qq & 1) * 8) = pk;
        }
    };

    v4f acc[4][2] = {};
    v8bf bpipe[3][2];
    float4 areg[2];

    {   // prologue: A(e0) issued first (oldest), then 6 B loads (taps 0..2)
        issueA(e0, areg);
#pragma unroll
        for (int i = 0; i < 3; ++i) {
            const char* p = bbase + (size_t)e0 * ESTR14 + (size_t)i * SSTR14;
            bpipe[i][0] = *(const v8bf*)p;
            bpipe[i][1] = *(const v8bf*)(p + 256);
        }
        convertA(areg, ldsA);        // reg-dep drains areg (vmcnt<=6); bpipe stays
        BARRIER(6);                  // all 6 B prefetches remain in flight
    }

    // TAP(S): compute tap (e,S); prefetch tap (9e+S+3)'s 2 B frags.
#define TAP(S) do { \
        v8bf b0 = bpipe[(S) % 3][0]; \
        v8bf b1 = bpipe[(S) % 3][1]; \
        const int _so = (((S) / 3) * 16 + ((S) % 3)) * 16; \
        v8bf a0 = *(const v8bf*)(Acur + aoff[0] + _so); \
        v8bf a1 = *(const v8bf*)(Acur + aoff[1] + _so); \
        v8bf a2 = *(const v8bf*)(Acur + aoff[2] + _so); \
        v8bf a3 = *(const v8bf*)(Acur + aoff[3] + _so); \
        __builtin_amdgcn_s_setprio(1); \
        acc[0][0] = __builtin_amdgcn_mfma_f32_16x16x32_bf16(a0, b0, acc[0][0], 0, 0, 0); \
        acc[0][1] = __builtin_amdgcn_mfma_f32_16x16x32_bf16(a0, b1, acc[0][1], 0, 0, 0); \
        acc[1][0] = __builtin_amdgcn_mfma_f32_16x16x32_bf16(a1, b0, acc[1][0], 0, 0, 0); \
        acc[1][1] = __builtin_amdgcn_mfma_f32_16x16x32_bf16(a1, b1, acc[1][1], 0, 0, 0); \
        acc[2][0] = __builtin_amdgcn_mfma_f32_16x16x32_bf16(a2, b0, acc[2][0], 0, 0, 0); \
        acc[2][1] = __builtin_amdgcn_mfma_f32_16x16x32_bf16(a2, b1, acc[2][1], 0, 0, 0); \
        acc[3][0] = __builtin_amdgcn_mfma_f32_16x16x32_bf16(a3, b0, acc[3][0], 0, 0, 0); \
        acc[3][1] = __builtin_amdgcn_mfma_f32_16x16x32_bf16(a3, b1, acc[3][1], 0, 0, 0); \
        __builtin_amdgcn_s_setprio(0); \
        if ((S) <= 5) { \
            const char* _p = bptr + (size_t)((S) + 3) * SSTR14; \
            bpipe[(S) % 3][0] = *(const v8bf*)_p; \
            bpipe[(S) % 3][1] = *(const v8bf*)(_p + 256); \
        } else if (e < e0 + 11) { \
            const char* _p = bptr + ESTR14 + (size_t)((S) - 6) * SSTR14; \
            bpipe[(S) % 3][0] = *(const v8bf*)_p; \
            bpipe[(S) % 3][1] = *(const v8bf*)(_p + 256); \
        } \
    } while (0)

#pragma unroll 1
    for (int e = e0; e < e0 + 12; ++e) {
        const char* Acur = ldsA + (e & 1) * ABUF14;
        const char* bptr = bbase + (size_t)e * ESTR14;
        TAP(0); TAP(1); TAP(2);
        if (e < e0 + 11) issueA(e + 1, areg);
        TAP(3); TAP(4); TAP(5); TAP(6);
        if (e < e0 + 11) convertA(areg, ldsA + ((e + 1) & 1) * ABUF14);  // drains areg
        TAP(7); TAP(8);
        if (e < e0 + 11) BARRIER(6);     // 6 next-ec2 B prefetches stay in flight
    }
#undef TAP

    // ---- fragment-dump store: fully coalesced 256B wave stores ----
    u32* Pd = P + ((size_t)(q * 128 + b)) * 12288;
#pragma unroll
    for (int nj = 0; nj < 2; ++nj)
#pragma unroll
        for (int mi = 0; mi < 4; ++mi)
#pragma unroll
            for (int rp = 0; rp < 2; ++rp) {
                u32 pk = (u32)f2bf(acc[mi][nj][rp * 2]) |
                         ((u32)f2bf(acc[mi][nj][rp * 2 + 1]) << 16);
                Pd[((((size_t)wid * 2 + nj) * 4 + mi) * 2 + rp) * 64 + lane] = pk;
            }
}

// ---------------------------------------------------------------------------
// ke2: merge K-halves (fragment order), BN + gelu + dot(zpk) + sigmoid.
// grid (128 b, 2 conv), 768 thr mirroring kc17c's fragment geometry.
// ---------------------------------------------------------------------------
__global__ __launch_bounds__(768) void ke2(const u32* __restrict__ P,
                                           const u16* __restrict__ zpk,
                                           const float* __restrict__ br,  const float* __restrict__ bnr_g,
                                           const float* __restrict__ bnr_b, const float* __restrict__ bnr_m,
                                           const float* __restrict__ bnr_v,
                                           const float* __restrict__ bi,  const float* __restrict__ bni_g,
                                           const float* __restrict__ bni_b, const float* __restrict__ bni_m,
                                           const float* __restrict__ bni_v,
                                           const float* __restrict__ c,
                                           float* __restrict__ out) {
    const int b    = blockIdx.x;
    const int conv = blockIdx.y;
    const int tid  = threadIdx.x;
    const int lane = tid & 63;
    const int wid  = tid >> 6;          // 0..11
    const int l15  = lane & 15;
    const int h    = lane >> 4;

    const float* bcp = conv ? bi    : br;
    const float* gp  = conv ? bni_g : bnr_g;
    const float* bbp = conv ? bni_b : bnr_b;
    const float* mp  = conv ? bni_m : bnr_m;
    const float* vp  = conv ? bni_v : bnr_v;

    const u32* P0 = P + ((size_t)(conv * 128 + b)) * 12288;
    const u32* P1 = P + ((size_t)((2 + conv) * 128 + b)) * 12288;

    float sum = 0.f;
#pragma unroll
    for (int nj = 0; nj < 2; ++nj) {
        const int o = wid * 32 + nj * 16 + l15;
        const float sc  = gp[o] * rsqrtf(vp[o] + EPSF);
        const float sh2 = (bcp[o] - mp[o]) * sc + bbp[o];
        const u16* zb = zpk + ((size_t)b * 384 + o) * 64;
#pragma unroll
        for (int mi = 0; mi < 4; ++mi) {
            ushort4 zw = *(const ushort4*)(zb + mi * 16 + h * 4);
#pragma unroll
            for (int rp = 0; rp < 2; ++rp) {
                size_t idx = ((((size_t)wid * 2 + nj) * 4 + mi) * 2 + rp) * 64 + lane;
                u32 a0 = P0[idx], a1 = P1[idx];
#pragma unroll
                for (int k = 0; k < 2; ++k) {
                    int reg = rp * 2 + k;
                    float cv = bf2f((u16)(k ? (a0 >> 16) : (a0 & 0xffff)))
                             + bf2f((u16)(k ? (a1 >> 16) : (a1 & 0xffff)));
                    float y = fmaf(cv, sc, sh2);
                    u16 zu = (reg == 0) ? zw.x : (reg == 1) ? zw.y : (reg == 2) ? zw.z : zw.w;
                    sum = fmaf(gelu_exact(y), bf2f(zu), sum);
                }
            }
        }
    }
#pragma unroll
    for (int off = 32; off >= 1; off >>= 1) sum += __shfl_down(sum, off, 64);

    __shared__ float redF[12];
    if (lane == 0) redF[wid] = sum;
    __syncthreads();
    if (tid == 0) {
        float t = 0.f;
#pragma unroll
        for (int w12 = 0; w12 < 12; ++w12) t += redF[w12];
        out[conv * 128 + b] = 1.f / (1.f + expf(-t / c[0]));
    }
}

extern "C" void kernel_launch(void* const* d_in, const int* in_sizes, int n_in,
                              void* d_out, int out_size, void* d_ws, size_t ws_size,
                              hipStream_t stream) {
    const float* z_r   = (const float*)d_in[0];
    const float* z_i   = (const float*)d_in[1];
    const float* x_r   = (const float*)d_in[2];
    const float* x_i   = (const float*)d_in[3];
    const float* fz_w  = (const float*)d_in[4];
    const float* fz_b  = (const float*)d_in[5];
    const float* ln_g  = (const float*)d_in[6];
    const float* ln_b  = (const float*)d_in[7];
    const float* wr    = (const float*)d_in[8];
    const float* br    = (const float*)d_in[9];
    const float* bnr_g = (const float*)d_in[10];
    const float* bnr_b = (const float*)d_in[11];
    const float* bnr_m = (const float*)d_in[12];
    const float* bnr_v = (const float*)d_in[13];
    const float* wi    = (const float*)d_in[14];
    const float* bi    = (const float*)d_in[15];
    const float* bni_g = (const float*)d_in[16];
    const float* bni_b = (const float*)d_in[17];
    const float* bni_m = (const float*)d_in[18];
    const float* bni_v = (const float*)d_in[19];
    const float* c     = (const float*)d_in[20];

    // ws (bytes): Bz [0, 1179648) | Bw [+10616832) | zpk [+6291456) | P [+25165824)
    u16* Bz  = (u16*)d_ws;
    u16* Bw  = (u16*)((char*)d_ws + 1179648);
    u16* zpk = (u16*)((char*)d_ws + 1179648 + 10616832);
    u32* P   = (u32*)((char*)d_ws + 1179648 + 10616832 + 6291456);

    kprep_z<<<288, 256, 0, stream>>>(fz_w, Bz);
    kprep_w<<<768, 256, 0, stream>>>(wr, wi, Bw);
    kz2<<<dim3(2, 128), 384, 0, stream>>>(z_r, z_i, Bz, fz_b, ln_g, ln_b, zpk);
    kc17c<<<dim3(4, 128), 768, 0, stream>>>(x_r, x_i, Bw, P);
    ke2<<<dim3(128, 2), 768, 0, stream>>>(P, zpk,
                                          br, bnr_g, bnr_b, bnr_m, bnr_v,
                                          bi, bni_g, bni_b, bni_m, bni_v,
                                          c, (float*)d_out);
}

// Round 23
// 163.831 us; speedup vs baseline: 1.7823x; 1.0567x over previous
//
#include <hip/hip_runtime.h>
#include <hip/hip_bf16.h>
#include <math.h>

#define EPSF 1e-5f

typedef __bf16 v8bf __attribute__((ext_vector_type(8)));
typedef float  v4f  __attribute__((ext_vector_type(4)));
typedef unsigned int u32;
typedef unsigned short u16;

__device__ __forceinline__ float gelu_exact(float x) {
    return 0.5f * x * (1.0f + erff(x * 0.70710678f));
}
__device__ __forceinline__ u16 f2bf(float f) {   // RNE
    u32 u = __float_as_uint(f);
    return (u16)((u + 0x7fffu + ((u >> 16) & 1u)) >> 16);
}
__device__ __forceinline__ float bf2f(u16 u) {
    return __uint_as_float(((u32)u) << 16);
}
__device__ __forceinline__ void gload16(const void* g, void* l) {
    __builtin_amdgcn_global_load_lds((const __attribute__((address_space(1))) u32*)g,
                                     (__attribute__((address_space(3))) u32*)l, 16, 0, 0);
}

// counted-vmcnt barrier: allow N vector-mem ops outstanding, drain LDS ops.
#define BARRIER(N) do { \
    asm volatile("s_waitcnt vmcnt(" #N ") lgkmcnt(0)" ::: "memory"); \
    __builtin_amdgcn_s_barrier(); \
} while (0)

// ---------------------------------------------------------------------------
// Prep: fz_w[o][1536] f32 -> Bz[ec2][h][n][8] bf16 (coalesced reads)
// ---------------------------------------------------------------------------
__global__ __launch_bounds__(256) void kprep_z(const float* __restrict__ fz_w,
                                               u16* __restrict__ Bz) {
    int idx = blockIdx.x * 256 + threadIdx.x;   // 0 .. 73727
    int n = idx / 192;
    int r = idx % 192;
    int ec2 = r >> 2;
    int h = r & 3;
    const float* src = fz_w + (size_t)n * 1536 + ec2 * 32 + h * 8;
    float4 v0 = *(const float4*)src;
    float4 v1 = *(const float4*)(src + 4);
    uint4 pk;
    pk.x = (u32)f2bf(v0.x) | ((u32)f2bf(v0.y) << 16);
    pk.y = (u32)f2bf(v0.z) | ((u32)f2bf(v0.w) << 16);
    pk.z = (u32)f2bf(v1.x) | ((u32)f2bf(v1.y) << 16);
    pk.w = (u32)f2bf(v1.z) | ((u32)f2bf(v1.w) << 16);
    size_t slot = ((size_t)(ec2 * 4 + h) * 384 + n);
    *(uint4*)(Bz + slot * 8) = pk;
}

// ---------------------------------------------------------------------------
// Prep: w[n][e][3][3] f32 -> Bw[conv][s][ec2][h][n][8] bf16.
// ---------------------------------------------------------------------------
__global__ __launch_bounds__(256) void kprep_w(const float* __restrict__ wr,
                                               const float* __restrict__ wi,
                                               u16* __restrict__ Bw) {
    __shared__ float wsm[6912];
    const int tid = threadIdx.x;
    const int n = blockIdx.x >> 1;
    const int conv = blockIdx.x & 1;
    const float* w = (conv ? wi : wr) + (size_t)n * 6912;
#pragma unroll
    for (int k = 0; k < 7; ++k) {
        int sl = tid + k * 256;
        if (sl < 1728) ((float4*)wsm)[sl] = ((const float4*)w)[sl];
    }
    __syncthreads();
#pragma unroll
    for (int k = 0; k < 4; ++k) {
        int sl = tid + k * 256;          // (s*24+ec2)*4 + h
        if (sl < 864) {
            int h = sl & 3;
            int r = sl >> 2;
            int ec2 = r % 24;
            int s = r / 24;
            int ch0 = ec2 * 32 + h * 8;
            u16 tmp[8];
#pragma unroll
            for (int e = 0; e < 8; ++e) tmp[e] = f2bf(wsm[(ch0 + e) * 9 + s]);
            uint4 pk;
            pk.x = (u32)tmp[0] | ((u32)tmp[1] << 16);
            pk.y = (u32)tmp[2] | ((u32)tmp[3] << 16);
            pk.z = (u32)tmp[4] | ((u32)tmp[5] << 16);
            pk.w = (u32)tmp[6] | ((u32)tmp[7] << 16);
            size_t slot = ((size_t)conv * 864 + sl) * 384 + n;
            *(uint4*)(Bw + slot * 8) = pk;
        }
    }
}

// ---------------------------------------------------------------------------
// kz2: z = gelu(LN(concat(z_r,z_i) @ fz_w^T + fz_b)) via MFMA.
// grid (2 t-halves, 128 b), 384 thr = 6 waves. Writes zpk[b][o][t(64)] bf16.
// ---------------------------------------------------------------------------
#define ZB_BUF 24576
#define ZA_BUF 2048

__global__ __launch_bounds__(384, 1) void kz2(const float* __restrict__ z_r,
                                              const float* __restrict__ z_i,
                                              const u16* __restrict__ Bz,
                                              const float* __restrict__ fz_b,
                                              const float* __restrict__ ln_g,
                                              const float* __restrict__ ln_b,
                                              u16* __restrict__ zpk) {
    const int th = blockIdx.x;
    const int b  = blockIdx.y;
    const int tid  = threadIdx.x;
    const int lane = tid & 63;
    const int wid  = tid >> 6;
    const int l15  = lane & 15;
    const int h    = lane >> 4;

    __shared__ __align__(16) char lds[3 * ZB_BUF + 2 * ZA_BUF];   // 77824
    char* ldsZB = lds;
    char* ldsZA = lds + 3 * ZB_BUF;
    __shared__ float redS[6 * 32], redQ[6 * 32], mu_s[32], rs_s[32];

    const float* zr_b = z_r + (size_t)b * (64 * 768);
    const float* zi_b = z_i + (size_t)b * (64 * 768);

    int boff[4];
#pragma unroll
    for (int nj = 0; nj < 4; ++nj) {
        int n = wid * 64 + nj * 16 + l15;
        boff[nj] = h * 6144 + n * 16;
    }
    int zaoff[2];
#pragma unroll
    for (int mi = 0; mi < 2; ++mi)
        zaoff[mi] = h * 512 + (mi * 16 + l15) * 16;

    auto stageZB = [&](int ec2, char* buf) {       // 4 gload16 / thread
        const char* src = (const char*)(Bz + (size_t)ec2 * 1536 * 8);
#pragma unroll
        for (int k = 0; k < 4; ++k) {
            int sl = tid + k * 384;
            gload16(src + sl * 16, buf + sl * 16);
        }
    };
    auto issueZA = [&](int ec2, float4* zr) {      // 1 load / thread (uniform)
        const float* zsrc = (ec2 < 24) ? zr_b : zi_b;
        const int ch0 = (ec2 < 24 ? ec2 : ec2 - 24) * 32;
        int sl = tid & 255;
        int row = sl >> 3, qq = sl & 7;
        zr[0] = *(const float4*)(zsrc + (size_t)(th * 32 + row) * 768 + ch0 + qq * 4);
    };
    auto convertZA = [&](const float4* zr, char* buf) {
        int sl = tid & 255;
        int row = sl >> 3, qq = sl & 7;
        ushort4 pk;
        pk.x = f2bf(zr[0].x); pk.y = f2bf(zr[0].y);
        pk.z = f2bf(zr[0].z); pk.w = f2bf(zr[0].w);
        *(ushort4*)(buf + (qq >> 1) * 512 + row * 16 + (qq & 1) * 8) = pk;
    };

    v4f acc[2][4] = {};

    auto comp = [&](char* curA, char* curB) {
        v8bf a[2], bfv[4];
#pragma unroll
        for (int mi = 0; mi < 2; ++mi) a[mi] = *(const v8bf*)(curA + zaoff[mi]);
#pragma unroll
        for (int nj = 0; nj < 4; ++nj) bfv[nj] = *(const v8bf*)(curB + boff[nj]);
        __builtin_amdgcn_s_setprio(1);
#pragma unroll
        for (int mi = 0; mi < 2; ++mi)
#pragma unroll
            for (int nj = 0; nj < 4; ++nj)
                acc[mi][nj] = __builtin_amdgcn_mfma_f32_16x16x32_bf16(a[mi], bfv[nj], acc[mi][nj], 0, 0, 0);
        __builtin_amdgcn_s_setprio(0);
    };

    float4 zreg[1];
    {
        issueZA(0, zreg);
        stageZB(0, ldsZB);
        stageZB(1, ldsZB + ZB_BUF);
        convertZA(zreg, ldsZA);      // waits ZA(0)
        issueZA(1, zreg);
        BARRIER(5);                  // allow ZB(1)=4 + ZA(1)=1
    }
#pragma unroll 1
    for (int t = 0; t < 46; ++t) {
        stageZB(t + 2, ldsZB + ((t + 2) % 3) * ZB_BUF);
        comp(ldsZA + (t & 1) * ZA_BUF, ldsZB + (t % 3) * ZB_BUF);
        convertZA(zreg, ldsZA + ((t + 1) & 1) * ZA_BUF);  // waits ZA(t+1): vmcnt(4)
        issueZA(t + 2, zreg);
        BARRIER(5);                  // allow ZB(t+2)=4 + ZA(t+2)=1; drains ZB(t+1)
    }
    {   // t = 46
        comp(ldsZA + (46 & 1) * ZA_BUF, ldsZB + (46 % 3) * ZB_BUF);
        convertZA(zreg, ldsZA + (47 & 1) * ZA_BUF);       // waits ZA(47): vmcnt(0)
        BARRIER(0);
    }
    comp(ldsZA + (47 & 1) * ZA_BUF, ldsZB + (47 % 3) * ZB_BUF);

    // ---- bias + LN stats (rows 0..31 local) ----
    float fzb[4], lng[4], lnb[4];
#pragma unroll
    for (int nj = 0; nj < 4; ++nj) {
        int o = wid * 64 + nj * 16 + l15;
        fzb[nj] = fz_b[o]; lng[nj] = ln_g[o]; lnb[nj] = ln_b[o];
    }
#pragma unroll
    for (int mi = 0; mi < 2; ++mi)
#pragma unroll
        for (int nj = 0; nj < 4; ++nj)
#pragma unroll
            for (int reg = 0; reg < 4; ++reg)
                acc[mi][nj][reg] += fzb[nj];

#pragma unroll
    for (int mi = 0; mi < 2; ++mi) {
#pragma unroll
        for (int reg = 0; reg < 4; ++reg) {
            float s = 0.f, q = 0.f;
#pragma unroll
            for (int nj = 0; nj < 4; ++nj) {
                float v = acc[mi][nj][reg];
                s += v; q += v * v;
            }
#pragma unroll
            for (int m = 0; m < 4; ++m) {
                s += __shfl_xor(s, 1 << m, 64);
                q += __shfl_xor(q, 1 << m, 64);
            }
            if (l15 == 0) {
                int row = mi * 16 + h * 4 + reg;
                redS[wid * 32 + row] = s;
                redQ[wid * 32 + row] = q;
            }
        }
    }
    __syncthreads();
    if (tid < 32) {
        float s = 0.f, q = 0.f;
#pragma unroll
        for (int w6 = 0; w6 < 6; ++w6) { s += redS[w6 * 32 + tid]; q += redQ[w6 * 32 + tid]; }
        float mu = s * (1.0f / 384.0f);
        float var = q * (1.0f / 384.0f) - mu * mu;
        mu_s[tid] = mu;
        rs_s[tid] = rsqrtf(var + EPSF);
    }
    __syncthreads();

    // ---- LN + gelu -> zpk[b][o][t] ----
#pragma unroll
    for (int mi = 0; mi < 2; ++mi)
#pragma unroll
        for (int nj = 0; nj < 4; ++nj) {
            int o = wid * 64 + nj * 16 + l15;
            u32* dst = (u32*)zpk + ((size_t)b * 384 + o) * 32 + th * 16 + mi * 8 + h * 2;
#pragma unroll
            for (int rp = 0; rp < 2; ++rp) {
                float zv[2];
#pragma unroll
                for (int k = 0; k < 2; ++k) {
                    int reg = rp * 2 + k;
                    int row = mi * 16 + h * 4 + reg;
                    float v = (acc[mi][nj][reg] - mu_s[row]) * rs_s[row] * lng[nj] + lnb[nj];
                    zv[k] = gelu_exact(v);
                }
                dst[rp] = (u32)f2bf(zv[0]) | ((u32)f2bf(zv[1]) << 16);
            }
        }
}

// ---------------------------------------------------------------------------
// kc14: implicit-GEMM cropped conv; one block per (conv,b) covering full
// M=64 x N=384. 768 thr = 12 waves, wave tile 64x32 (8 MFMA : 4 ds_read).
// B in registers (3-tap x 2-frag prefetch). Reg-staged A, [h][176][16B].
// 24 counted barriers. grid 256. BEST MEASURED: 120.1 us, total 164.0.
// ---------------------------------------------------------------------------
#define APL14  2816            // A h-plane stride (176*16)
#define ABUF14 (4 * APL14)     // 11264 per ec2 buffer
#define SSTR14 589824          // 24 * 24576 : tap-s stride in Bw
#define ESTR14 24576           // ec2 stride in Bw

__global__ __launch_bounds__(768, 3) void kc14(const float* __restrict__ x_r,
                                               const float* __restrict__ x_i,
                                               const u16* __restrict__ Bw,
                                               const u16* __restrict__ zpk,
                                               const float* __restrict__ br,  const float* __restrict__ bnr_g,
                                               const float* __restrict__ bnr_b, const float* __restrict__ bnr_m,
                                               const float* __restrict__ bnr_v,
                                               const float* __restrict__ bi,  const float* __restrict__ bni_g,
                                               const float* __restrict__ bni_b, const float* __restrict__ bni_m,
                                               const float* __restrict__ bni_v,
                                               float* __restrict__ part) {
    const int conv = blockIdx.x;
    const int b    = blockIdx.y;
    const int tid  = threadIdx.x;
    const int lane = tid & 63;
    const int wid  = tid >> 6;          // 0..11 = 32-col group
    const int l15  = lane & 15;
    const int h    = lane >> 4;         // 0..3

    __shared__ __align__(16) char ldsA[2 * ABUF14];   // 22528
    __shared__ float redF[12];

    const float* x  = conv ? x_i : x_r;
    const float* xb = x + (size_t)b * (256 * 768);

    // B fragment base: this thread's (h, col0) within a tap slab.
    const char* bbase = (const char*)(Bw + (size_t)conv * (864 * 384 * 8))
                      + (size_t)h * 6144 + (wid * 32 + l15) * 16;

    int aoff[4];
#pragma unroll
    for (int mi = 0; mi < 4; ++mi) {
        int p = mi * 16 + l15;
        int i = p >> 3, j = p & 7;
        aoff[mi] = h * APL14 + (i * 16 + j + 3) * 16;
    }

    auto issueA = [&](int ec2, float4* ar) {          // 2 loads/thread (wrapped dup)
#pragma unroll
        for (int k = 0; k < 2; ++k) {
            int sl = tid + k * 768;
            if (sl >= 1408) sl -= 1408;
            int row = sl >> 3, qq = sl & 7;
            ar[k] = *(const float4*)(xb + (size_t)(48 + row) * 768 + ec2 * 32 + qq * 4);
        }
    };
    auto convertA = [&](const float4* ar, char* buf) {
#pragma unroll
        for (int k = 0; k < 2; ++k) {
            int sl = tid + k * 768;
            if (sl >= 1408) sl -= 1408;
            int row = sl >> 3, qq = sl & 7;
            ushort4 pk;
            pk.x = f2bf(ar[k].x); pk.y = f2bf(ar[k].y);
            pk.z = f2bf(ar[k].z); pk.w = f2bf(ar[k].w);
            *(ushort4*)(buf + (qq >> 1) * APL14 + row * 16 + (qq & 1) * 8) = pk;
        }
    };

    v4f acc[4][2] = {};
    v8bf bpipe[3][2];
    float4 areg[2];

    {   // prologue: A(0) first (oldest), then 6 B prefetches (taps 0..2)
        issueA(0, areg);
#pragma unroll
        for (int i = 0; i < 3; ++i) {
            const char* p = bbase + (size_t)i * SSTR14;
            bpipe[i][0] = *(const v8bf*)p;
            bpipe[i][1] = *(const v8bf*)(p + 256);
        }
        convertA(areg, ldsA);        // reg-dep drains areg (vmcnt<=6); bpipe stays
        BARRIER(6);                  // all 6 B prefetches remain in flight
    }

    // TAP(S): compute tap (e,S); prefetch tap (9e+S+3)'s 2 B frags.
#define TAP(S) do { \
        v8bf b0 = bpipe[(S) % 3][0]; \
        v8bf b1 = bpipe[(S) % 3][1]; \
        const int _so = (((S) / 3) * 16 + ((S) % 3)) * 16; \
        v8bf a0 = *(const v8bf*)(Acur + aoff[0] + _so); \
        v8bf a1 = *(const v8bf*)(Acur + aoff[1] + _so); \
        v8bf a2 = *(const v8bf*)(Acur + aoff[2] + _so); \
        v8bf a3 = *(const v8bf*)(Acur + aoff[3] + _so); \
        __builtin_amdgcn_s_setprio(1); \
        acc[0][0] = __builtin_amdgcn_mfma_f32_16x16x32_bf16(a0, b0, acc[0][0], 0, 0, 0); \
        acc[0][1] = __builtin_amdgcn_mfma_f32_16x16x32_bf16(a0, b1, acc[0][1], 0, 0, 0); \
        acc[1][0] = __builtin_amdgcn_mfma_f32_16x16x32_bf16(a1, b0, acc[1][0], 0, 0, 0); \
        acc[1][1] = __builtin_amdgcn_mfma_f32_16x16x32_bf16(a1, b1, acc[1][1], 0, 0, 0); \
        acc[2][0] = __builtin_amdgcn_mfma_f32_16x16x32_bf16(a2, b0, acc[2][0], 0, 0, 0); \
        acc[2][1] = __builtin_amdgcn_mfma_f32_16x16x32_bf16(a2, b1, acc[2][1], 0, 0, 0); \
        acc[3][0] = __builtin_amdgcn_mfma_f32_16x16x32_bf16(a3, b0, acc[3][0], 0, 0, 0); \
        acc[3][1] = __builtin_amdgcn_mfma_f32_16x16x32_bf16(a3, b1, acc[3][1], 0, 0, 0); \
        __builtin_amdgcn_s_setprio(0); \
        if ((S) <= 5) { \
            const char* _p = bptr + (size_t)((S) + 3) * SSTR14; \
            bpipe[(S) % 3][0] = *(const v8bf*)_p; \
            bpipe[(S) % 3][1] = *(const v8bf*)(_p + 256); \
        } else if (e < 23) { \
            const char* _p = bptr + ESTR14 + (size_t)((S) - 6) * SSTR14; \
            bpipe[(S) % 3][0] = *(const v8bf*)_p; \
            bpipe[(S) % 3][1] = *(const v8bf*)(_p + 256); \
        } \
    } while (0)

#pragma unroll 1
    for (int e = 0; e < 24; ++e) {
        const char* Acur = ldsA + (e & 1) * ABUF14;
        const char* bptr = bbase + (size_t)e * ESTR14;
        TAP(0); TAP(1); TAP(2);
        if (e < 23) issueA(e + 1, areg);
        TAP(3); TAP(4); TAP(5); TAP(6);
        if (e < 23) convertA(areg, ldsA + ((e + 1) & 1) * ABUF14);  // drains areg
        TAP(7); TAP(8);
        if (e < 23) BARRIER(6);      // 6 next-ec2 B prefetches stay in flight
    }
#undef TAP

    // ---- BN + gelu + dot(zpk) ----
    const float* bcp = conv ? bi    : br;
    const float* gp  = conv ? bni_g : bnr_g;
    const float* bbp = conv ? bni_b : bnr_b;
    const float* mp  = conv ? bni_m : bnr_m;
    const float* vp  = conv ? bni_v : bnr_v;

    float sum = 0.f;
#pragma unroll
    for (int nj = 0; nj < 2; ++nj) {
        const int o = wid * 32 + nj * 16 + l15;
        const float sc  = gp[o] * rsqrtf(vp[o] + EPSF);
        const float sh2 = (bcp[o] - mp[o]) * sc + bbp[o];
        const u16* zb = zpk + ((size_t)b * 384 + o) * 64;
#pragma unroll
        for (int mi = 0; mi < 4; ++mi) {
            ushort4 zw = *(const ushort4*)(zb + mi * 16 + h * 4);
#pragma unroll
            for (int reg = 0; reg < 4; ++reg) {
                float y = fmaf(acc[mi][nj][reg], sc, sh2);
                u16 zu = (reg == 0) ? zw.x : (reg == 1) ? zw.y : (reg == 2) ? zw.z : zw.w;
                sum = fmaf(gelu_exact(y), bf2f(zu), sum);
            }
        }
    }
#pragma unroll
    for (int off = 32; off >= 1; off >>= 1) sum += __shfl_down(sum, off, 64);

    if (lane == 0) redF[wid] = sum;
    __syncthreads();
    if (tid == 0) {
        float t = 0.f;
#pragma unroll
        for (int w12 = 0; w12 < 12; ++w12) t += redF[w12];
        part[(size_t)conv * 128 + b] = t;
    }
}

// ---------------------------------------------------------------------------
// kr: sigmoid of per-(conv,b) totals.
// ---------------------------------------------------------------------------
__global__ __launch_bounds__(256) void kr(const float* __restrict__ part,
                                          const float* __restrict__ c,
                                          float* __restrict__ out) {
    int v = threadIdx.x;     // 0..255 = conv*128+b
    out[v] = 1.f / (1.f + expf(-part[v] / c[0]));
}

extern "C" void kernel_launch(void* const* d_in, const int* in_sizes, int n_in,
                              void* d_out, int out_size, void* d_ws, size_t ws_size,
                              hipStream_t stream) {
    const float* z_r   = (const float*)d_in[0];
    const float* z_i   = (const float*)d_in[1];
    const float* x_r   = (const float*)d_in[2];
    const float* x_i   = (const float*)d_in[3];
    const float* fz_w  = (const float*)d_in[4];
    const float* fz_b  = (const float*)d_in[5];
    const float* ln_g  = (const float*)d_in[6];
    const float* ln_b  = (const float*)d_in[7];
    const float* wr    = (const float*)d_in[8];
    const float* br    = (const float*)d_in[9];
    const float* bnr_g = (const float*)d_in[10];
    const float* bnr_b = (const float*)d_in[11];
    const float* bnr_m = (const float*)d_in[12];
    const float* bnr_v = (const float*)d_in[13];
    const float* wi    = (const float*)d_in[14];
    const float* bi    = (const float*)d_in[15];
    const float* bni_g = (const float*)d_in[16];
    const float* bni_b = (const float*)d_in[17];
    const float* bni_m = (const float*)d_in[18];
    const float* bni_v = (const float*)d_in[19];
    const float* c     = (const float*)d_in[20];

    // ws (bytes): Bz [0, 1179648) | Bw [+10616832) | zpk [+6291456) | part [+1024)
    u16*   Bz   = (u16*)d_ws;
    u16*   Bw   = (u16*)((char*)d_ws + 1179648);
    u16*   zpk  = (u16*)((char*)d_ws + 1179648 + 10616832);
    float* part = (float*)((char*)d_ws + 1179648 + 10616832 + 6291456);

    kprep_z<<<288, 256, 0, stream>>>(fz_w, Bz);
    kprep_w<<<768, 256, 0, stream>>>(wr, wi, Bw);
    kz2<<<dim3(2, 128), 384, 0, stream>>>(z_r, z_i, Bz, fz_b, ln_g, ln_b, zpk);
    kc14<<<dim3(2, 128), 768, 0, stream>>>(x_r, x_i, Bw, zpk,
                                           br, bnr_g, bnr_b, bnr_m, bnr_v,
                                           bi, bni_g, bni_b, bni_m, bni_v,
                                           part);
    kr<<<1, 256, 0, stream>>>(part, c, (float*)d_out);
}

// Round 24
// 156.445 us; speedup vs baseline: 1.8664x; 1.0472x over previous
//
#include <hip/hip_runtime.h>
#include <hip/hip_bf16.h>
#include <math.h>

#define EPSF 1e-5f

typedef __bf16 v8bf __attribute__((ext_vector_type(8)));
typedef float  v4f  __attribute__((ext_vector_type(4)));
typedef unsigned int u32;
typedef unsigned short u16;

__device__ __forceinline__ float gelu_exact(float x) {
    return 0.5f * x * (1.0f + erff(x * 0.70710678f));
}
__device__ __forceinline__ u16 f2bf(float f) {   // RNE
    u32 u = __float_as_uint(f);
    return (u16)((u + 0x7fffu + ((u >> 16) & 1u)) >> 16);
}
__device__ __forceinline__ float bf2f(u16 u) {
    return __uint_as_float(((u32)u) << 16);
}
__device__ __forceinline__ void gload16(const void* g, void* l) {
    __builtin_amdgcn_global_load_lds((const __attribute__((address_space(1))) u32*)g,
                                     (__attribute__((address_space(3))) u32*)l, 16, 0, 0);
}

// counted-vmcnt barrier: allow N vector-mem ops outstanding, drain LDS ops.
#define BARRIER(N) do { \
    asm volatile("s_waitcnt vmcnt(" #N ") lgkmcnt(0)" ::: "memory"); \
    __builtin_amdgcn_s_barrier(); \
} while (0)

// ---------------------------------------------------------------------------
// Merged prep: blocks [0,768): w -> Bw slabs; blocks [768,1056): fz_w -> Bz.
// ---------------------------------------------------------------------------
__global__ __launch_bounds__(256) void kprep(const float* __restrict__ wr,
                                             const float* __restrict__ wi,
                                             const float* __restrict__ fz_w,
                                             u16* __restrict__ Bw,
                                             u16* __restrict__ Bz) {
    const int tid = threadIdx.x;
    if (blockIdx.x < 768) {
        __shared__ float wsm[6912];
        const int n = blockIdx.x >> 1;
        const int conv = blockIdx.x & 1;
        const float* w = (conv ? wi : wr) + (size_t)n * 6912;
#pragma unroll
        for (int k = 0; k < 7; ++k) {
            int sl = tid + k * 256;
            if (sl < 1728) ((float4*)wsm)[sl] = ((const float4*)w)[sl];
        }
        __syncthreads();
#pragma unroll
        for (int k = 0; k < 4; ++k) {
            int sl = tid + k * 256;          // (s*24+ec2)*4 + h
            if (sl < 864) {
                int h = sl & 3;
                int r = sl >> 2;
                int ec2 = r % 24;
                int s = r / 24;
                int ch0 = ec2 * 32 + h * 8;
                u16 tmp[8];
#pragma unroll
                for (int e = 0; e < 8; ++e) tmp[e] = f2bf(wsm[(ch0 + e) * 9 + s]);
                uint4 pk;
                pk.x = (u32)tmp[0] | ((u32)tmp[1] << 16);
                pk.y = (u32)tmp[2] | ((u32)tmp[3] << 16);
                pk.z = (u32)tmp[4] | ((u32)tmp[5] << 16);
                pk.w = (u32)tmp[6] | ((u32)tmp[7] << 16);
                size_t slot = ((size_t)conv * 864 + sl) * 384 + n;
                *(uint4*)(Bw + slot * 8) = pk;
            }
        }
    } else {
        int idx = (blockIdx.x - 768) * 256 + tid;   // 0 .. 73727
        int n = idx / 192;
        int r = idx % 192;
        int ec2 = r >> 2;
        int h = r & 3;
        const float* src = fz_w + (size_t)n * 1536 + ec2 * 32 + h * 8;
        float4 v0 = *(const float4*)src;
        float4 v1 = *(const float4*)(src + 4);
        uint4 pk;
        pk.x = (u32)f2bf(v0.x) | ((u32)f2bf(v0.y) << 16);
        pk.y = (u32)f2bf(v0.z) | ((u32)f2bf(v0.w) << 16);
        pk.z = (u32)f2bf(v1.x) | ((u32)f2bf(v1.y) << 16);
        pk.w = (u32)f2bf(v1.z) | ((u32)f2bf(v1.w) << 16);
        size_t slot = ((size_t)(ec2 * 4 + h) * 384 + n);
        *(uint4*)(Bz + slot * 8) = pk;
    }
}

// ---------------------------------------------------------------------------
// kz2: z = gelu(LN(concat(z_r,z_i) @ fz_w^T + fz_b)) via MFMA.
// grid (2 t-halves, 128 b), 384 thr = 6 waves. Writes zpk[b][o][t(64)] bf16.
// ---------------------------------------------------------------------------
#define ZB_BUF 24576
#define ZA_BUF 2048

__global__ __launch_bounds__(384, 1) void kz2(const float* __restrict__ z_r,
                                              const float* __restrict__ z_i,
                                              const u16* __restrict__ Bz,
                                              const float* __restrict__ fz_b,
                                              const float* __restrict__ ln_g,
                                              const float* __restrict__ ln_b,
                                              u16* __restrict__ zpk) {
    const int th = blockIdx.x;
    const int b  = blockIdx.y;
    const int tid  = threadIdx.x;
    const int lane = tid & 63;
    const int wid  = tid >> 6;
    const int l15  = lane & 15;
    const int h    = lane >> 4;

    __shared__ __align__(16) char lds[3 * ZB_BUF + 2 * ZA_BUF];   // 77824
    char* ldsZB = lds;
    char* ldsZA = lds + 3 * ZB_BUF;
    __shared__ float redS[6 * 32], redQ[6 * 32], mu_s[32], rs_s[32];

    const float* zr_b = z_r + (size_t)b * (64 * 768);
    const float* zi_b = z_i + (size_t)b * (64 * 768);

    int boff[4];
#pragma unroll
    for (int nj = 0; nj < 4; ++nj) {
        int n = wid * 64 + nj * 16 + l15;
        boff[nj] = h * 6144 + n * 16;
    }
    int zaoff[2];
#pragma unroll
    for (int mi = 0; mi < 2; ++mi)
        zaoff[mi] = h * 512 + (mi * 16 + l15) * 16;

    auto stageZB = [&](int ec2, char* buf) {       // 4 gload16 / thread
        const char* src = (const char*)(Bz + (size_t)ec2 * 1536 * 8);
#pragma unroll
        for (int k = 0; k < 4; ++k) {
            int sl = tid + k * 384;
            gload16(src + sl * 16, buf + sl * 16);
        }
    };
    auto issueZA = [&](int ec2, float4* zr) {      // 1 load / thread (uniform)
        const float* zsrc = (ec2 < 24) ? zr_b : zi_b;
        const int ch0 = (ec2 < 24 ? ec2 : ec2 - 24) * 32;
        int sl = tid & 255;
        int row = sl >> 3, qq = sl & 7;
        zr[0] = *(const float4*)(zsrc + (size_t)(th * 32 + row) * 768 + ch0 + qq * 4);
    };
    auto convertZA = [&](const float4* zr, char* buf) {
        int sl = tid & 255;
        int row = sl >> 3, qq = sl & 7;
        ushort4 pk;
        pk.x = f2bf(zr[0].x); pk.y = f2bf(zr[0].y);
        pk.z = f2bf(zr[0].z); pk.w = f2bf(zr[0].w);
        *(ushort4*)(buf + (qq >> 1) * 512 + row * 16 + (qq & 1) * 8) = pk;
    };

    v4f acc[2][4] = {};

    auto comp = [&](char* curA, char* curB) {
        v8bf a[2], bfv[4];
#pragma unroll
        for (int mi = 0; mi < 2; ++mi) a[mi] = *(const v8bf*)(curA + zaoff[mi]);
#pragma unroll
        for (int nj = 0; nj < 4; ++nj) bfv[nj] = *(const v8bf*)(curB + boff[nj]);
        __builtin_amdgcn_s_setprio(1);
#pragma unroll
        for (int mi = 0; mi < 2; ++mi)
#pragma unroll
            for (int nj = 0; nj < 4; ++nj)
                acc[mi][nj] = __builtin_amdgcn_mfma_f32_16x16x32_bf16(a[mi], bfv[nj], acc[mi][nj], 0, 0, 0);
        __builtin_amdgcn_s_setprio(0);
    };

    float4 zreg[1];
    {
        issueZA(0, zreg);
        stageZB(0, ldsZB);
        stageZB(1, ldsZB + ZB_BUF);
        convertZA(zreg, ldsZA);      // waits ZA(0)
        issueZA(1, zreg);
        BARRIER(5);                  // allow ZB(1)=4 + ZA(1)=1
    }
#pragma unroll 1
    for (int t = 0; t < 46; ++t) {
        stageZB(t + 2, ldsZB + ((t + 2) % 3) * ZB_BUF);
        comp(ldsZA + (t & 1) * ZA_BUF, ldsZB + (t % 3) * ZB_BUF);
        convertZA(zreg, ldsZA + ((t + 1) & 1) * ZA_BUF);  // waits ZA(t+1): vmcnt(4)
        issueZA(t + 2, zreg);
        BARRIER(5);                  // allow ZB(t+2)=4 + ZA(t+2)=1; drains ZB(t+1)
    }
    {   // t = 46
        comp(ldsZA + (46 & 1) * ZA_BUF, ldsZB + (46 % 3) * ZB_BUF);
        convertZA(zreg, ldsZA + (47 & 1) * ZA_BUF);       // waits ZA(47): vmcnt(0)
        BARRIER(0);
    }
    comp(ldsZA + (47 & 1) * ZA_BUF, ldsZB + (47 % 3) * ZB_BUF);

    // ---- bias + LN stats (rows 0..31 local) ----
    float fzb[4], lng[4], lnb[4];
#pragma unroll
    for (int nj = 0; nj < 4; ++nj) {
        int o = wid * 64 + nj * 16 + l15;
        fzb[nj] = fz_b[o]; lng[nj] = ln_g[o]; lnb[nj] = ln_b[o];
    }
#pragma unroll
    for (int mi = 0; mi < 2; ++mi)
#pragma unroll
        for (int nj = 0; nj < 4; ++nj)
#pragma unroll
            for (int reg = 0; reg < 4; ++reg)
                acc[mi][nj][reg] += fzb[nj];

#pragma unroll
    for (int mi = 0; mi < 2; ++mi) {
#pragma unroll
        for (int reg = 0; reg < 4; ++reg) {
            float s = 0.f, q = 0.f;
#pragma unroll
            for (int nj = 0; nj < 4; ++nj) {
                float v = acc[mi][nj][reg];
                s += v; q += v * v;
            }
#pragma unroll
            for (int m = 0; m < 4; ++m) {
                s += __shfl_xor(s, 1 << m, 64);
                q += __shfl_xor(q, 1 << m, 64);
            }
            if (l15 == 0) {
                int row = mi * 16 + h * 4 + reg;
                redS[wid * 32 + row] = s;
                redQ[wid * 32 + row] = q;
            }
        }
    }
    __syncthreads();
    if (tid < 32) {
        float s = 0.f, q = 0.f;
#pragma unroll
        for (int w6 = 0; w6 < 6; ++w6) { s += redS[w6 * 32 + tid]; q += redQ[w6 * 32 + tid]; }
        float mu = s * (1.0f / 384.0f);
        float var = q * (1.0f / 384.0f) - mu * mu;
        mu_s[tid] = mu;
        rs_s[tid] = rsqrtf(var + EPSF);
    }
    __syncthreads();

    // ---- LN + gelu -> zpk[b][o][t] ----
#pragma unroll
    for (int mi = 0; mi < 2; ++mi)
#pragma unroll
        for (int nj = 0; nj < 4; ++nj) {
            int o = wid * 64 + nj * 16 + l15;
            u32* dst = (u32*)zpk + ((size_t)b * 384 + o) * 32 + th * 16 + mi * 8 + h * 2;
#pragma unroll
            for (int rp = 0; rp < 2; ++rp) {
                float zv[2];
#pragma unroll
                for (int k = 0; k < 2; ++k) {
                    int reg = rp * 2 + k;
                    int row = mi * 16 + h * 4 + reg;
                    float v = (acc[mi][nj][reg] - mu_s[row]) * rs_s[row] * lng[nj] + lnb[nj];
                    zv[k] = gelu_exact(v);
                }
                dst[rp] = (u32)f2bf(zv[0]) | ((u32)f2bf(zv[1]) << 16);
            }
        }
}

// ---------------------------------------------------------------------------
// kc14: implicit-GEMM cropped conv; one block per (conv,b) covering full
// M=64 x N=384. 768 thr = 12 waves, wave tile 64x32 (8 MFMA : 4 ds_read).
// B in registers (3-tap x 2-frag prefetch). Reg-staged A, [h][176][16B].
// 24 counted barriers. grid 256. Sigmoid fused (writes out directly).
// ---------------------------------------------------------------------------
#define APL14  2816            // A h-plane stride (176*16)
#define ABUF14 (4 * APL14)     // 11264 per ec2 buffer
#define SSTR14 589824          // 24 * 24576 : tap-s stride in Bw
#define ESTR14 24576           // ec2 stride in Bw

__global__ __launch_bounds__(768, 3) void kc14(const float* __restrict__ x_r,
                                               const float* __restrict__ x_i,
                                               const u16* __restrict__ Bw,
                                               const u16* __restrict__ zpk,
                                               const float* __restrict__ br,  const float* __restrict__ bnr_g,
                                               const float* __restrict__ bnr_b, const float* __restrict__ bnr_m,
                                               const float* __restrict__ bnr_v,
                                               const float* __restrict__ bi,  const float* __restrict__ bni_g,
                                               const float* __restrict__ bni_b, const float* __restrict__ bni_m,
                                               const float* __restrict__ bni_v,
                                               const float* __restrict__ c,
                                               float* __restrict__ out) {
    const int conv = blockIdx.x;
    const int b    = blockIdx.y;
    const int tid  = threadIdx.x;
    const int lane = tid & 63;
    const int wid  = tid >> 6;          // 0..11 = 32-col group
    const int l15  = lane & 15;
    const int h    = lane >> 4;         // 0..3

    __shared__ __align__(16) char ldsA[2 * ABUF14];   // 22528
    __shared__ float redF[12];

    const float* x  = conv ? x_i : x_r;
    const float* xb = x + (size_t)b * (256 * 768);

    // B fragment base: this thread's (h, col0) within a tap slab.
    const char* bbase = (const char*)(Bw + (size_t)conv * (864 * 384 * 8))
                      + (size_t)h * 6144 + (wid * 32 + l15) * 16;

    int aoff[4];
#pragma unroll
    for (int mi = 0; mi < 4; ++mi) {
        int p = mi * 16 + l15;
        int i = p >> 3, j = p & 7;
        aoff[mi] = h * APL14 + (i * 16 + j + 3) * 16;
    }

    auto issueA = [&](int ec2, float4* ar) {          // 2 loads/thread (wrapped dup)
#pragma unroll
        for (int k = 0; k < 2; ++k) {
            int sl = tid + k * 768;
            if (sl >= 1408) sl -= 1408;
            int row = sl >> 3, qq = sl & 7;
            ar[k] = *(const float4*)(xb + (size_t)(48 + row) * 768 + ec2 * 32 + qq * 4);
        }
    };
    auto convertA = [&](const float4* ar, char* buf) {
#pragma unroll
        for (int k = 0; k < 2; ++k) {
            int sl = tid + k * 768;
            if (sl >= 1408) sl -= 1408;
            int row = sl >> 3, qq = sl & 7;
            ushort4 pk;
            pk.x = f2bf(ar[k].x); pk.y = f2bf(ar[k].y);
            pk.z = f2bf(ar[k].z); pk.w = f2bf(ar[k].w);
            *(ushort4*)(buf + (qq >> 1) * APL14 + row * 16 + (qq & 1) * 8) = pk;
        }
    };

    v4f acc[4][2] = {};
    v8bf bpipe[3][2];
    float4 areg[2];

    {   // prologue: A(0) first (oldest), then 6 B prefetches (taps 0..2)
        issueA(0, areg);
#pragma unroll
        for (int i = 0; i < 3; ++i) {
            const char* p = bbase + (size_t)i * SSTR14;
            bpipe[i][0] = *(const v8bf*)p;
            bpipe[i][1] = *(const v8bf*)(p + 256);
        }
        convertA(areg, ldsA);        // reg-dep drains areg (vmcnt<=6); bpipe stays
        BARRIER(6);                  // all 6 B prefetches remain in flight
    }

    // TAP(S): compute tap (e,S); prefetch tap (9e+S+3)'s 2 B frags.
#define TAP(S) do { \
        v8bf b0 = bpipe[(S) % 3][0]; \
        v8bf b1 = bpipe[(S) % 3][1]; \
        const int _so = (((S) / 3) * 16 + ((S) % 3)) * 16; \
        v8bf a0 = *(const v8bf*)(Acur + aoff[0] + _so); \
        v8bf a1 = *(const v8bf*)(Acur + aoff[1] + _so); \
        v8bf a2 = *(const v8bf*)(Acur + aoff[2] + _so); \
        v8bf a3 = *(const v8bf*)(Acur + aoff[3] + _so); \
        __builtin_amdgcn_s_setprio(1); \
        acc[0][0] = __builtin_amdgcn_mfma_f32_16x16x32_bf16(a0, b0, acc[0][0], 0, 0, 0); \
        acc[0][1] = __builtin_amdgcn_mfma_f32_16x16x32_bf16(a0, b1, acc[0][1], 0, 0, 0); \
        acc[1][0] = __builtin_amdgcn_mfma_f32_16x16x32_bf16(a1, b0, acc[1][0], 0, 0, 0); \
        acc[1][1] = __builtin_amdgcn_mfma_f32_16x16x32_bf16(a1, b1, acc[1][1], 0, 0, 0); \
        acc[2][0] = __builtin_amdgcn_mfma_f32_16x16x32_bf16(a2, b0, acc[2][0], 0, 0, 0); \
        acc[2][1] = __builtin_amdgcn_mfma_f32_16x16x32_bf16(a2, b1, acc[2][1], 0, 0, 0); \
        acc[3][0] = __builtin_amdgcn_mfma_f32_16x16x32_bf16(a3, b0, acc[3][0], 0, 0, 0); \
        acc[3][1] = __builtin_amdgcn_mfma_f32_16x16x32_bf16(a3, b1, acc[3][1], 0, 0, 0); \
        __builtin_amdgcn_s_setprio(0); \
        if ((S) <= 5) { \
            const char* _p = bptr + (size_t)((S) + 3) * SSTR14; \
            bpipe[(S) % 3][0] = *(const v8bf*)_p; \
            bpipe[(S) % 3][1] = *(const v8bf*)(_p + 256); \
        } else if (e < 23) { \
            const char* _p = bptr + ESTR14 + (size_t)((S) - 6) * SSTR14; \
            bpipe[(S) % 3][0] = *(const v8bf*)_p; \
            bpipe[(S) % 3][1] = *(const v8bf*)(_p + 256); \
        } \
    } while (0)

#pragma unroll 1
    for (int e = 0; e < 24; ++e) {
        const char* Acur = ldsA + (e & 1) * ABUF14;
        const char* bptr = bbase + (size_t)e * ESTR14;
        TAP(0); TAP(1); TAP(2);
        if (e < 23) issueA(e + 1, areg);
        TAP(3); TAP(4); TAP(5); TAP(6);
        if (e < 23) convertA(areg, ldsA + ((e + 1) & 1) * ABUF14);  // drains areg
        TAP(7); TAP(8);
        if (e < 23) BARRIER(6);      // 6 next-ec2 B prefetches stay in flight
    }
#undef TAP

    // ---- BN + gelu + dot(zpk) ----
    const float* bcp = conv ? bi    : br;
    const float* gp  = conv ? bni_g : bnr_g;
    const float* bbp = conv ? bni_b : bnr_b;
    const float* mp  = conv ? bni_m : bnr_m;
    const float* vp  = conv ? bni_v : bnr_v;

    float sum = 0.f;
#pragma unroll
    for (int nj = 0; nj < 2; ++nj) {
        const int o = wid * 32 + nj * 16 + l15;
        const float sc  = gp[o] * rsqrtf(vp[o] + EPSF);
        const float sh2 = (bcp[o] - mp[o]) * sc + bbp[o];
        const u16* zb = zpk + ((size_t)b * 384 + o) * 64;
#pragma unroll
        for (int mi = 0; mi < 4; ++mi) {
            ushort4 zw = *(const ushort4*)(zb + mi * 16 + h * 4);
#pragma unroll
            for (int reg = 0; reg < 4; ++reg) {
                float y = fmaf(acc[mi][nj][reg], sc, sh2);
                u16 zu = (reg == 0) ? zw.x : (reg == 1) ? zw.y : (reg == 2) ? zw.z : zw.w;
                sum = fmaf(gelu_exact(y), bf2f(zu), sum);
            }
        }
    }
#pragma unroll
    for (int off = 32; off >= 1; off >>= 1) sum += __shfl_down(sum, off, 64);

    if (lane == 0) redF[wid] = sum;
    __syncthreads();
    if (tid == 0) {
        float t = 0.f;
#pragma unroll
        for (int w12 = 0; w12 < 12; ++w12) t += redF[w12];
        out[conv * 128 + b] = 1.f / (1.f + expf(-t / c[0]));   // fused sigmoid
    }
}

extern "C" void kernel_launch(void* const* d_in, const int* in_sizes, int n_in,
                              void* d_out, int out_size, void* d_ws, size_t ws_size,
                              hipStream_t stream) {
    const float* z_r   = (const float*)d_in[0];
    const float* z_i   = (const float*)d_in[1];
    const float* x_r   = (const float*)d_in[2];
    const float* x_i   = (const float*)d_in[3];
    const float* fz_w  = (const float*)d_in[4];
    const float* fz_b  = (const float*)d_in[5];
    const float* ln_g  = (const float*)d_in[6];
    const float* ln_b  = (const float*)d_in[7];
    const float* wr    = (const float*)d_in[8];
    const float* br    = (const float*)d_in[9];
    const float* bnr_g = (const float*)d_in[10];
    const float* bnr_b = (const float*)d_in[11];
    const float* bnr_m = (const float*)d_in[12];
    const float* bnr_v = (const float*)d_in[13];
    const float* wi    = (const float*)d_in[14];
    const float* bi    = (const float*)d_in[15];
    const float* bni_g = (const float*)d_in[16];
    const float* bni_b = (const float*)d_in[17];
    const float* bni_m = (const float*)d_in[18];
    const float* bni_v = (const float*)d_in[19];
    const float* c     = (const float*)d_in[20];

    // ws (bytes): Bz [0, 1179648) | Bw [+10616832) | zpk [+6291456)
    u16* Bz  = (u16*)d_ws;
    u16* Bw  = (u16*)((char*)d_ws + 1179648);
    u16* zpk = (u16*)((char*)d_ws + 1179648 + 10616832);

    kprep<<<1056, 256, 0, stream>>>(wr, wi, fz_w, Bw, Bz);
    kz2<<<dim3(2, 128), 384, 0, stream>>>(z_r, z_i, Bz, fz_b, ln_g, ln_b, zpk);
    kc14<<<dim3(2, 128), 768, 0, stream>>>(x_r, x_i, Bw, zpk,
                                           br, bnr_g, bnr_b, bnr_m, bnr_v,
                                           bi, bni_g, bni_b, bni_m, bni_v,
                                           c, (float*)d_out);
}